// Round 1
// baseline (2140.041 us; speedup 1.0000x reference)
//
#include <hip/hip_runtime.h>
#include <cstdint>
#include <cmath>

// Problem constants (match reference)
#define NN 100000   // nodes
#define EE 500000   // edges
// DN=64, DE=64, D=128, TD=64, K_self = 192
#define CAP 64      // incidence-list capacity per node (Poisson(10): P(deg>64) ~ 1e-50)

typedef __attribute__((ext_vector_type(8))) short short8v;   // 8 bf16 (4 VGPRs)
typedef __attribute__((ext_vector_type(4))) float f32x4;     // MFMA accumulator

// float -> bf16 round-to-nearest-even (bit trick; inputs finite)
static __device__ __forceinline__ unsigned short f2bf_rne(float x) {
    unsigned u = __float_as_uint(x);
    u += 0x7FFFu + ((u >> 16) & 1u);
    return (unsigned short)(u >> 16);
}

// ---------------------------------------------------------------------------
// Build per-node incidence lists (replaces f32 scatter-atomics with a gather).
__global__ __launch_bounds__(256) void k_build(const int* __restrict__ src,
                                               const int* __restrict__ dst,
                                               int* __restrict__ pos,
                                               int* __restrict__ eidx) {
    int e = blockIdx.x * 256 + threadIdx.x;
    if (e >= EE) return;
    int s = src[e], d = dst[e];
    int sl = atomicAdd(&pos[s], 1);
    if (sl < CAP) eidx[(size_t)s * CAP + sl] = (e << 1) | 1;
    int dl = atomicAdd(&pos[d], 1);
    if (dl < CAP) eidx[(size_t)d * CAP + dl] = (e << 1);
}

// ---------------------------------------------------------------------------
// combine_feats: feat_src[e] = [nfeat[src[e]], efeat[e]], feat_dst likewise.
__global__ __launch_bounds__(256) void k_combine(const float* __restrict__ nfeat,
                                                 const float* __restrict__ efeat,
                                                 const int* __restrict__ src,
                                                 const int* __restrict__ dst,
                                                 float* __restrict__ outS,
                                                 float* __restrict__ outD) {
    int idx = blockIdx.x * 256 + threadIdx.x;   // over EE*32 float4s
    int e = idx >> 5, c4 = idx & 31;
    size_t o = (size_t)e * 128 + c4 * 4;
    if (c4 < 16) {
        int s = src[e], d = dst[e];
        float4 vs = *(const float4*)(nfeat + (size_t)s * 64 + c4 * 4);
        float4 vd = *(const float4*)(nfeat + (size_t)d * 64 + c4 * 4);
        *(float4*)(outS + o) = vs;
        *(float4*)(outD + o) = vd;
    } else {
        float4 v = *(const float4*)(efeat + (size_t)e * 64 + (c4 - 16) * 4);
        *(float4*)(outS + o) = v;
        *(float4*)(outD + o) = v;
    }
}

// ---------------------------------------------------------------------------
// Aggregation: one wave per node; lane holds 2 of 128 channels in registers.
__global__ __launch_bounds__(256) void k_agg(const float* __restrict__ featS,
                                             const float* __restrict__ featD,
                                             const int* __restrict__ pos,
                                             const int* __restrict__ eidx,
                                             float* __restrict__ mean) {
    int w = (blockIdx.x * 256 + threadIdx.x) >> 6;   // node id
    int lane = threadIdx.x & 63;
    if (w >= NN) return;
    int d = pos[w];
    int dd = min(d, CAP);
    const int* lst = eidx + (size_t)w * CAP;
    float ax = 0.f, ay = 0.f;
    for (int j = 0; j < dd; ++j) {
        int entry = lst[j];                         // wave-uniform
        const float* base = (entry & 1) ? featD : featS;
        float2 v = *(const float2*)(base + ((size_t)(entry >> 1)) * 128 + lane * 2);
        ax += v.x; ay += v.y;
    }
    float inv = 1.0f / fmaxf((float)d, 1.0f);
    float2 r; r.x = ax * inv; r.y = ay * inv;
    *(float2*)(mean + (size_t)w * 128 + lane * 2) = r;
}

// ---------------------------------------------------------------------------
// Weight prep: W [K][128] fp32 row-major -> transposed split-bf16 H/L [128][K].
// hi = truncation (top 16 bits), lo = RNE(x - hi).  Error after 3-term MFMA
// reconstruction ~2^-16 relative (dropped lo*lo term only).
__global__ __launch_bounds__(256) void k_wt(const float* __restrict__ W, int K,
                                            unsigned short* __restrict__ H,
                                            unsigned short* __restrict__ L) {
    int idx = blockIdx.x * 256 + threadIdx.x;
    if (idx >= K * 128) return;
    int k = idx >> 7, c = idx & 127;
    float x = W[idx];
    unsigned u = __float_as_uint(x);
    H[(size_t)c * K + k] = (unsigned short)(u >> 16);
    float r = x - __uint_as_float(u & 0xFFFF0000u);
    L[(size_t)c * K + k] = f2bf_rne(r);
}

// ---------------------------------------------------------------------------
// neigh_proj = mean @ W_neigh + b_neigh  via split-bf16 MFMA (3 terms).
// Tile: 128 nodes x 128 cols, 4 waves x (32 rows x 128 cols), K panels of 32.
// Fragment maps (m89/m92-verified): A row=lane&15,k=(lane>>4)*8+j;
// B col=lane&15,same k; D col=lane&15,row=(lane>>4)*4+reg.
__global__ __launch_bounds__(256) void k_neigh_mfma(
        const float* __restrict__ mean,
        const unsigned short* __restrict__ WtH,   // [128 cols][128 k] bf16 hi
        const unsigned short* __restrict__ WtL,   // lo
        const float* __restrict__ bias,
        float* __restrict__ outp) {
    __shared__ unsigned short Xh[128][40];   // stride 40 shorts = 80B -> 2-way bank alias (free)
    __shared__ unsigned short Xl[128][40];
    __shared__ unsigned short Wh[128][40];
    __shared__ unsigned short Wl[128][40];

    const int tid  = threadIdx.x;
    const int n0   = blockIdx.x * 128;
    const int lane = tid & 63;
    const int w    = tid >> 6;       // wave 0..3 -> rows w*32..w*32+31
    const int krow = lane & 15;
    const int kgrp = lane >> 4;

    f32x4 acc[2][8] = {};

    for (int ch = 0; ch < 4; ++ch) {
        const int k0 = ch * 32;
        // stage W panel [128 cols][32 k] hi+lo (pure bf16 copy)
#pragma unroll
        for (int r = 0; r < 2; ++r) {
            int v = tid + r * 256;
            int c = v >> 2, part = v & 3;
            size_t g = (size_t)c * 128 + k0 + part * 8;
            *(uint4*)&Wh[c][part * 8] = *(const uint4*)(WtH + g);
            *(uint4*)&Wl[c][part * 8] = *(const uint4*)(WtL + g);
        }
        // stage X panel [128 rows][32 k]: fp32 -> hi/lo bf16
#pragma unroll
        for (int r = 0; r < 4; ++r) {
            int v = tid + r * 256;
            int row = v >> 3, q = v & 7;
            int n = min(n0 + row, NN - 1);
            float4 x = *(const float4*)(mean + (size_t)n * 128 + k0 + q * 4);
            unsigned u0 = __float_as_uint(x.x), u1 = __float_as_uint(x.y);
            unsigned u2 = __float_as_uint(x.z), u3 = __float_as_uint(x.w);
            uint2 hw, lw;
            hw.x = (u0 >> 16) | (u1 & 0xFFFF0000u);
            hw.y = (u2 >> 16) | (u3 & 0xFFFF0000u);
            float r0 = x.x - __uint_as_float(u0 & 0xFFFF0000u);
            float r1 = x.y - __uint_as_float(u1 & 0xFFFF0000u);
            float r2 = x.z - __uint_as_float(u2 & 0xFFFF0000u);
            float r3 = x.w - __uint_as_float(u3 & 0xFFFF0000u);
            lw.x = (unsigned)f2bf_rne(r0) | ((unsigned)f2bf_rne(r1) << 16);
            lw.y = (unsigned)f2bf_rne(r2) | ((unsigned)f2bf_rne(r3) << 16);
            *(uint2*)&Xh[row][q * 4] = hw;
            *(uint2*)&Xl[row][q * 4] = lw;
        }
        __syncthreads();

        short8v Ah[2], Al[2];
#pragma unroll
        for (int rt = 0; rt < 2; ++rt) {
            int row = w * 32 + rt * 16 + krow;
            Ah[rt] = *(const short8v*)&Xh[row][kgrp * 8];
            Al[rt] = *(const short8v*)&Xl[row][kgrp * 8];
        }
#pragma unroll
        for (int ct = 0; ct < 8; ++ct) {
            int c = ct * 16 + krow;
            short8v Bh = *(const short8v*)&Wh[c][kgrp * 8];
            short8v Bl = *(const short8v*)&Wl[c][kgrp * 8];
#pragma unroll
            for (int rt = 0; rt < 2; ++rt) {
                acc[rt][ct] = __builtin_amdgcn_mfma_f32_16x16x32_bf16(Ah[rt], Bh, acc[rt][ct], 0, 0, 0);
                acc[rt][ct] = __builtin_amdgcn_mfma_f32_16x16x32_bf16(Ah[rt], Bl, acc[rt][ct], 0, 0, 0);
                acc[rt][ct] = __builtin_amdgcn_mfma_f32_16x16x32_bf16(Al[rt], Bh, acc[rt][ct], 0, 0, 0);
            }
        }
        __syncthreads();
    }

    float bcol[8];
#pragma unroll
    for (int ct = 0; ct < 8; ++ct) bcol[ct] = bias[ct * 16 + krow];
#pragma unroll
    for (int rt = 0; rt < 2; ++rt) {
#pragma unroll
        for (int j = 0; j < 4; ++j) {
            int n = n0 + w * 32 + rt * 16 + kgrp * 4 + j;
            if (n < NN) {
                float* op = outp + (size_t)n * 128;
#pragma unroll
                for (int ct = 0; ct < 8; ++ct)
                    op[ct * 16 + krow] = acc[rt][ct][j] + bcol[ct];
            }
        }
    }
}

// ---------------------------------------------------------------------------
// Edge update via split-bf16 MFMA.  Rows = 64 edges x {src,dst} = 128, cols=128,
// K=192: chunks 0-3 from feat rows (fp32->hi/lo in staging), chunks 4-5 from
// the per-block time encoding (computed once, split into teH/teL).
// out = relu(concat(prev, te) @ W_self + b_self + neigh_proj[endpoint]).
// In-place safe: all global reads of this block's rows finish before the
// chunk-3 post-stage barrier; epilogue writes come after the k-loop.
__global__ __launch_bounds__(256) void k_edge_mfma(
        const float* __restrict__ featS, const float* __restrict__ featD,
        float* __restrict__ outS, float* __restrict__ outD,
        const int* __restrict__ src, const int* __restrict__ dst,
        const float* __restrict__ ts,
        const unsigned short* __restrict__ WtH,   // [128 cols][192 k] bf16 hi
        const unsigned short* __restrict__ WtL,   // lo
        const float* __restrict__ bias,
        const float* __restrict__ neigh,
        const float* __restrict__ omega, const float* __restrict__ phase) {
    __shared__ unsigned short Xh[128][40];
    __shared__ unsigned short Xl[128][40];
    __shared__ unsigned short Wh[128][40];
    __shared__ unsigned short Wl[128][40];
    __shared__ unsigned short teH[64][72];   // stride 72 shorts = 144B -> 2-way alias
    __shared__ unsigned short teL[64][72];

    const int tid  = threadIdx.x;
    const int e0   = blockIdx.x * 64;
    const int lane = tid & 63;
    const int w    = tid >> 6;       // rows w*32..w*32+31 (rows 0-63 = src side)
    const int krow = lane & 15;
    const int kgrp = lane >> 4;

    // ---- time encoding: 64 edges x 64 td, split hi/lo bf16 ----
    {
        const int tl = tid & 63;
        const int j0 = (tid >> 6) * 16;
        const float tval = ts[min(e0 + tl, EE - 1)];
#pragma unroll
        for (int j = 0; j < 16; j += 2) {
            int jj = j0 + j;
            float c0 = cosf(fmaf(tval, omega[jj],     phase[jj]));
            float c1 = cosf(fmaf(tval, omega[jj + 1], phase[jj + 1]));
            unsigned u0 = __float_as_uint(c0), u1 = __float_as_uint(c1);
            *(unsigned*)&teH[tl][jj] = (u0 >> 16) | (u1 & 0xFFFF0000u);
            float r0 = c0 - __uint_as_float(u0 & 0xFFFF0000u);
            float r1 = c1 - __uint_as_float(u1 & 0xFFFF0000u);
            *(unsigned*)&teL[tl][jj] =
                (unsigned)f2bf_rne(r0) | ((unsigned)f2bf_rne(r1) << 16);
        }
    }

    f32x4 acc[2][8] = {};

    for (int ch = 0; ch < 6; ++ch) {
        const int k0 = ch * 32;
        // stage W panel [128 cols][32 k] hi+lo
#pragma unroll
        for (int r = 0; r < 2; ++r) {
            int v = tid + r * 256;
            int c = v >> 2, part = v & 3;
            size_t g = (size_t)c * 192 + k0 + part * 8;
            *(uint4*)&Wh[c][part * 8] = *(const uint4*)(WtH + g);
            *(uint4*)&Wl[c][part * 8] = *(const uint4*)(WtL + g);
        }
        if (ch < 4) {
            // stage X panel [128 rows][32 k]: fp32 -> hi/lo bf16
#pragma unroll
            for (int r = 0; r < 4; ++r) {
                int v = tid + r * 256;
                int row = v >> 3, q = v & 7;
                const float* fp = (row < 64) ? featS : featD;
                int e = min(e0 + (row & 63), EE - 1);
                float4 x = *(const float4*)(fp + (size_t)e * 128 + k0 + q * 4);
                unsigned u0 = __float_as_uint(x.x), u1 = __float_as_uint(x.y);
                unsigned u2 = __float_as_uint(x.z), u3 = __float_as_uint(x.w);
                uint2 hw, lw;
                hw.x = (u0 >> 16) | (u1 & 0xFFFF0000u);
                hw.y = (u2 >> 16) | (u3 & 0xFFFF0000u);
                float r0 = x.x - __uint_as_float(u0 & 0xFFFF0000u);
                float r1 = x.y - __uint_as_float(u1 & 0xFFFF0000u);
                float r2 = x.z - __uint_as_float(u2 & 0xFFFF0000u);
                float r3 = x.w - __uint_as_float(u3 & 0xFFFF0000u);
                lw.x = (unsigned)f2bf_rne(r0) | ((unsigned)f2bf_rne(r1) << 16);
                lw.y = (unsigned)f2bf_rne(r2) | ((unsigned)f2bf_rne(r3) << 16);
                *(uint2*)&Xh[row][q * 4] = hw;
                *(uint2*)&Xl[row][q * 4] = lw;
            }
        }
        __syncthreads();

        short8v Ah[2], Al[2];
        if (ch < 4) {
#pragma unroll
            for (int rt = 0; rt < 2; ++rt) {
                int row = w * 32 + rt * 16 + krow;
                Ah[rt] = *(const short8v*)&Xh[row][kgrp * 8];
                Al[rt] = *(const short8v*)&Xl[row][kgrp * 8];
            }
        } else {
            int kt = (ch - 4) * 32 + kgrp * 8;
#pragma unroll
            for (int rt = 0; rt < 2; ++rt) {
                int el = (w * 32 + rt * 16 + krow) & 63;   // edge-local (src & dst share te)
                Ah[rt] = *(const short8v*)&teH[el][kt];
                Al[rt] = *(const short8v*)&teL[el][kt];
            }
        }
#pragma unroll
        for (int ct = 0; ct < 8; ++ct) {
            int c = ct * 16 + krow;
            short8v Bh = *(const short8v*)&Wh[c][kgrp * 8];
            short8v Bl = *(const short8v*)&Wl[c][kgrp * 8];
#pragma unroll
            for (int rt = 0; rt < 2; ++rt) {
                acc[rt][ct] = __builtin_amdgcn_mfma_f32_16x16x32_bf16(Ah[rt], Bh, acc[rt][ct], 0, 0, 0);
                acc[rt][ct] = __builtin_amdgcn_mfma_f32_16x16x32_bf16(Ah[rt], Bl, acc[rt][ct], 0, 0, 0);
                acc[rt][ct] = __builtin_amdgcn_mfma_f32_16x16x32_bf16(Al[rt], Bh, acc[rt][ct], 0, 0, 0);
            }
        }
        __syncthreads();
    }

    // ---- epilogue: + b_self + neigh_proj[endpoint], relu, store in place ----
    float bcol[8];
#pragma unroll
    for (int ct = 0; ct < 8; ++ct) bcol[ct] = bias[ct * 16 + krow];
#pragma unroll
    for (int rt = 0; rt < 2; ++rt) {
#pragma unroll
        for (int j = 0; j < 4; ++j) {
            int row = w * 32 + rt * 16 + kgrp * 4 + j;
            int e = e0 + (row & 63);
            if (e < EE) {
                bool isS = row < 64;
                int node = isS ? src[e] : dst[e];
                const float* np = neigh + (size_t)node * 128;
                float* op = (isS ? outS : outD) + (size_t)e * 128;
#pragma unroll
                for (int ct = 0; ct < 8; ++ct) {
                    float v2 = acc[rt][ct][j] + bcol[ct] + np[ct * 16 + krow];
                    op[ct * 16 + krow] = fmaxf(v2, 0.f);
                }
            }
        }
    }
}

// ---------------------------------------------------------------------------
extern "C" void kernel_launch(void* const* d_in, const int* in_sizes, int n_in,
                              void* d_out, int out_size, void* d_ws, size_t ws_size,
                              hipStream_t stream) {
    const float* nfeat = (const float*)d_in[0];
    const float* efeat = (const float*)d_in[1];
    const int*   src   = (const int*)d_in[2];
    const int*   dst   = (const int*)d_in[3];
    const float* ts    = (const float*)d_in[4];
    const float* Wself[2]  = {(const float*)d_in[5],  (const float*)d_in[11]};
    const float* bself[2]  = {(const float*)d_in[6],  (const float*)d_in[12]};
    const float* Wneigh[2] = {(const float*)d_in[7],  (const float*)d_in[13]};
    const float* bneigh[2] = {(const float*)d_in[8],  (const float*)d_in[14]};
    const float* omega[2]  = {(const float*)d_in[9],  (const float*)d_in[15]};
    const float* phase[2]  = {(const float*)d_in[10], (const float*)d_in[16]};

    // d_out doubles as the edge-feature ping-pong storage (in-place layers).
    float* outS = (float*)d_out;                   // src_feat  [E,128]
    float* outD = outS + (size_t)EE * 128;         // dst_feat  [E,128]

    // workspace: mean | neigh | pos | eidx | split-bf16 weights (~128.8 MB)
    float* mean  = (float*)d_ws;
    float* neigh = mean + (size_t)NN * 128;
    int*   pos   = (int*)(neigh + (size_t)NN * 128);
    int*   eidx  = pos + NN;
    unsigned short* wb = (unsigned short*)(eidx + (size_t)NN * CAP);
    unsigned short* WsH[2] = {wb,                 wb + 2 * 128 * 192};
    unsigned short* WsL[2] = {wb + 128 * 192,     wb + 3 * 128 * 192};
    unsigned short* wn = wb + 4 * 128 * 192;
    unsigned short* WnH[2] = {wn,                 wn + 2 * 128 * 128};
    unsigned short* WnL[2] = {wn + 128 * 128,     wn + 3 * 128 * 128};

    hipMemsetAsync(pos, 0, NN * sizeof(int), stream);
    k_build<<<(EE + 255) / 256, 256, 0, stream>>>(src, dst, pos, eidx);
    k_combine<<<(EE * 32) / 256, 256, 0, stream>>>(nfeat, efeat, src, dst, outS, outD);
    for (int l = 0; l < 2; ++l) {
        k_wt<<<(192 * 128 + 255) / 256, 256, 0, stream>>>(Wself[l], 192, WsH[l], WsL[l]);
        k_wt<<<(128 * 128 + 255) / 256, 256, 0, stream>>>(Wneigh[l], 128, WnH[l], WnL[l]);
    }

    for (int l = 0; l < 2; ++l) {
        k_agg<<<(NN * 64 + 255) / 256, 256, 0, stream>>>(outS, outD, pos, eidx, mean);
        k_neigh_mfma<<<(NN + 127) / 128, 256, 0, stream>>>(mean, WnH[l], WnL[l], bneigh[l], neigh);
        k_edge_mfma<<<(EE + 63) / 64, 256, 0, stream>>>(outS, outD, outS, outD, src, dst, ts,
                                                        WsH[l], WsL[l], bself[l], neigh,
                                                        omega[l], phase[l]);
    }
}

// Round 2
// 2121.489 us; speedup vs baseline: 1.0087x; 1.0087x over previous
//
#include <hip/hip_runtime.h>
#include <cstdint>
#include <cmath>

// Problem constants (match reference)
#define NN 100000   // nodes
#define EE 500000   // edges
// DN=64, DE=64, D=128, TD=64, K_self = 192
#define CAP 64      // incidence-list capacity per node (Poisson(10): P(deg>64) ~ 1e-50)

typedef __attribute__((ext_vector_type(8))) short short8v;   // 8 bf16 (4 VGPRs)
typedef __attribute__((ext_vector_type(4))) float f32x4;     // MFMA accumulator

// float -> bf16 round-to-nearest-even (bit trick; inputs finite)
static __device__ __forceinline__ unsigned short f2bf_rne(float x) {
    unsigned u = __float_as_uint(x);
    u += 0x7FFFu + ((u >> 16) & 1u);
    return (unsigned short)(u >> 16);
}

// pack 8 consecutive floats into hi/lo bf16 vectors (hi=truncate, lo=RNE residual)
static __device__ __forceinline__ void split8(float4 a, float4 b,
                                              short8v* hi, short8v* lo) {
    union { short8v v; unsigned u[4]; } H, L;
    float f[8] = {a.x, a.y, a.z, a.w, b.x, b.y, b.z, b.w};
#pragma unroll
    for (int p = 0; p < 4; ++p) {
        unsigned u0 = __float_as_uint(f[2 * p]);
        unsigned u1 = __float_as_uint(f[2 * p + 1]);
        H.u[p] = (u0 >> 16) | (u1 & 0xFFFF0000u);
        float r0 = f[2 * p]     - __uint_as_float(u0 & 0xFFFF0000u);
        float r1 = f[2 * p + 1] - __uint_as_float(u1 & 0xFFFF0000u);
        L.u[p] = (unsigned)f2bf_rne(r0) | ((unsigned)f2bf_rne(r1) << 16);
    }
    *hi = H.v; *lo = L.v;
}

// ---------------------------------------------------------------------------
// Build per-node incidence lists (replaces f32 scatter-atomics with a gather).
__global__ __launch_bounds__(256) void k_build(const int* __restrict__ src,
                                               const int* __restrict__ dst,
                                               int* __restrict__ pos,
                                               int* __restrict__ eidx) {
    int e = blockIdx.x * 256 + threadIdx.x;
    if (e >= EE) return;
    int s = src[e], d = dst[e];
    int sl = atomicAdd(&pos[s], 1);
    if (sl < CAP) eidx[(size_t)s * CAP + sl] = (e << 1) | 1;
    int dl = atomicAdd(&pos[d], 1);
    if (dl < CAP) eidx[(size_t)d * CAP + dl] = (e << 1);
}

// ---------------------------------------------------------------------------
// Weight prep: W [K][128] fp32 row-major -> transposed split-bf16 H/L [128][K].
__global__ __launch_bounds__(256) void k_wt(const float* __restrict__ W, int K,
                                            unsigned short* __restrict__ H,
                                            unsigned short* __restrict__ L) {
    int idx = blockIdx.x * 256 + threadIdx.x;
    if (idx >= K * 128) return;
    int k = idx >> 7, c = idx & 127;
    float x = W[idx];
    unsigned u = __float_as_uint(x);
    H[(size_t)c * K + k] = (unsigned short)(u >> 16);
    float r = x - __uint_as_float(u & 0xFFFF0000u);
    L[(size_t)c * K + k] = f2bf_rne(r);
}

// ---------------------------------------------------------------------------
// Aggregation: one wave per node, half-wave per incidence entry (2 in flight),
// float4 per lane.  LAYER==1 gathers straight from nfeat/efeat (no combine
// materialization); LAYER==2 gathers from the ping-pong feature rows.
template <int LAYER>
__global__ __launch_bounds__(256) void k_agg(const float* __restrict__ featS,
                                             const float* __restrict__ featD,
                                             const float* __restrict__ nfeat,
                                             const float* __restrict__ efeat,
                                             const int* __restrict__ src,
                                             const int* __restrict__ dst,
                                             const int* __restrict__ pos,
                                             const int* __restrict__ eidx,
                                             float* __restrict__ mean) {
    int w = (blockIdx.x * 256 + threadIdx.x) >> 6;   // node id
    int lane = threadIdx.x & 63;
    if (w >= NN) return;
    int half = lane >> 5, cl = lane & 31;            // cl*4 .. cl*4+3 channels
    int d = pos[w];
    int dd = min(d, CAP);
    const int* lst = eidx + (size_t)w * CAP;
    float ax = 0.f, ay = 0.f, az = 0.f, aw = 0.f;
    for (int j = half; j < dd; j += 2) {
        int entry = lst[j];
        int e = entry >> 1, side = entry & 1;
        const float* p;
        if (LAYER == 1) {
            // contribution row = [nfeat[other], efeat[e]]
            if (cl < 16) {
                int other = side ? dst[e] : src[e];
                p = nfeat + (size_t)other * 64 + cl * 4;
            } else {
                p = efeat + (size_t)e * 64 + (cl - 16) * 4;
            }
        } else {
            p = (side ? featD : featS) + (size_t)e * 128 + cl * 4;
        }
        float4 v = *(const float4*)p;
        ax += v.x; ay += v.y; az += v.z; aw += v.w;
    }
    // combine the two half-wave partial sums
    ax += __shfl_xor(ax, 32); ay += __shfl_xor(ay, 32);
    az += __shfl_xor(az, 32); aw += __shfl_xor(aw, 32);
    if (half == 0) {
        float inv = 1.0f / fmaxf((float)d, 1.0f);
        float4 r; r.x = ax * inv; r.y = ay * inv; r.z = az * inv; r.w = aw * inv;
        *(float4*)(mean + (size_t)w * 128 + cl * 4) = r;
    }
}

// ---------------------------------------------------------------------------
// neigh_proj = mean @ W_neigh + b_neigh via split-bf16 MFMA, barrier-free:
// A fragments straight from global fp32 (split in registers), B fragments
// straight from global bf16 (L2-broadcast across blocks).  No LDS at all.
__global__ __launch_bounds__(256, 3) void k_neigh_mfma(
        const float* __restrict__ mean,
        const unsigned short* __restrict__ WtH,   // [128 cols][128 k] bf16 hi
        const unsigned short* __restrict__ WtL,   // lo
        const float* __restrict__ bias,
        float* __restrict__ outp) {
    const int tid  = threadIdx.x;
    const int n0   = blockIdx.x * 128;
    const int lane = tid & 63;
    const int w    = tid >> 6;       // rows w*32 .. w*32+31
    const int krow = lane & 15;
    const int kgrp = lane >> 4;

    const float* rb[2];
#pragma unroll
    for (int rt = 0; rt < 2; ++rt) {
        int n = min(n0 + w * 32 + rt * 16 + krow, NN - 1);
        rb[rt] = mean + (size_t)n * 128;
    }

    f32x4 acc[2][8] = {};
#pragma unroll
    for (int ch = 0; ch < 4; ++ch) {
        const int koff = ch * 32 + kgrp * 8;
        short8v Ah[2], Al[2];
#pragma unroll
        for (int rt = 0; rt < 2; ++rt) {
            float4 x0 = *(const float4*)(rb[rt] + koff);
            float4 x1 = *(const float4*)(rb[rt] + koff + 4);
            split8(x0, x1, &Ah[rt], &Al[rt]);
        }
#pragma unroll
        for (int ct = 0; ct < 8; ++ct) {
            int c = ct * 16 + krow;
            short8v Bh = *(const short8v*)(WtH + (size_t)c * 128 + koff);
            short8v Bl = *(const short8v*)(WtL + (size_t)c * 128 + koff);
#pragma unroll
            for (int rt = 0; rt < 2; ++rt) {
                acc[rt][ct] = __builtin_amdgcn_mfma_f32_16x16x32_bf16(Ah[rt], Bh, acc[rt][ct], 0, 0, 0);
                acc[rt][ct] = __builtin_amdgcn_mfma_f32_16x16x32_bf16(Ah[rt], Bl, acc[rt][ct], 0, 0, 0);
                acc[rt][ct] = __builtin_amdgcn_mfma_f32_16x16x32_bf16(Al[rt], Bh, acc[rt][ct], 0, 0, 0);
            }
        }
    }

    float bcol[8];
#pragma unroll
    for (int ct = 0; ct < 8; ++ct) bcol[ct] = bias[ct * 16 + krow];
#pragma unroll
    for (int rt = 0; rt < 2; ++rt) {
#pragma unroll
        for (int j = 0; j < 4; ++j) {
            int n = n0 + w * 32 + rt * 16 + kgrp * 4 + j;
            if (n < NN) {
                float* op = outp + (size_t)n * 128;
#pragma unroll
                for (int ct = 0; ct < 8; ++ct)
                    op[ct * 16 + krow] = acc[rt][ct][j] + bcol[ct];
            }
        }
    }
}

// ---------------------------------------------------------------------------
// Edge update via split-bf16 MFMA, barrier-free k-loop (single barrier for te).
// Rows = 64 edges x {src,dst} = 128, cols = 128, K = 192:
// chunks 0-3 A from global fp32 rows (LAYER==1: nfeat/efeat gather directly;
// LAYER==2: ping-pong feature rows), chunks 4-5 A from the te LDS buffers.
// B fragments from global bf16 (L2-broadcast).
// out = relu(concat(prev, te) @ W_self + b_self + neigh_proj[endpoint]).
// In-place safe (LAYER==2): each block only reads/writes its own 64 edge rows,
// and all A reads happen before the epilogue stores.
template <int LAYER>
__global__ __launch_bounds__(256, 3) void k_edge_mfma(
        const float* __restrict__ featS, const float* __restrict__ featD,
        const float* __restrict__ nfeat, const float* __restrict__ efeat,
        float* __restrict__ outS, float* __restrict__ outD,
        const int* __restrict__ src, const int* __restrict__ dst,
        const float* __restrict__ ts,
        const unsigned short* __restrict__ WtH,   // [128 cols][192 k] bf16 hi
        const unsigned short* __restrict__ WtL,   // lo
        const float* __restrict__ bias,
        const float* __restrict__ neigh,
        const float* __restrict__ omega, const float* __restrict__ phase) {
    __shared__ unsigned short teH[64][72];   // stride 72 shorts -> 2-way alias (free)
    __shared__ unsigned short teL[64][72];

    const int tid  = threadIdx.x;
    const int e0   = blockIdx.x * 64;
    const int lane = tid & 63;
    const int w    = tid >> 6;       // rows w*32..w*32+31 (rows 0-63 = src side)
    const int krow = lane & 15;
    const int kgrp = lane >> 4;

    // ---- time encoding: 64 edges x 64 td, split hi/lo bf16 ----
    {
        const int tl = tid & 63;
        const int j0 = (tid >> 6) * 16;
        const float tval = ts[min(e0 + tl, EE - 1)];
#pragma unroll
        for (int j = 0; j < 16; j += 2) {
            int jj = j0 + j;
            float c0 = cosf(fmaf(tval, omega[jj],     phase[jj]));
            float c1 = cosf(fmaf(tval, omega[jj + 1], phase[jj + 1]));
            unsigned u0 = __float_as_uint(c0), u1 = __float_as_uint(c1);
            *(unsigned*)&teH[tl][jj] = (u0 >> 16) | (u1 & 0xFFFF0000u);
            float r0 = c0 - __uint_as_float(u0 & 0xFFFF0000u);
            float r1 = c1 - __uint_as_float(u1 & 0xFFFF0000u);
            *(unsigned*)&teL[tl][jj] =
                (unsigned)f2bf_rne(r0) | ((unsigned)f2bf_rne(r1) << 16);
        }
    }
    __syncthreads();   // the ONLY barrier: te ready before chunks 4-5

    // per-lane A-row base pointers (2 rows: rt = 0,1)
    const float* rbN[2];   // LAYER==1: nfeat[endpoint] row ; LAYER==2: feat row
    const float* rbE[2];   // LAYER==1: efeat row
#pragma unroll
    for (int rt = 0; rt < 2; ++rt) {
        int row = w * 32 + rt * 16 + krow;
        int e = min(e0 + (row & 63), EE - 1);
        if (LAYER == 1) {
            int node = (row < 64) ? src[e] : dst[e];
            rbN[rt] = nfeat + (size_t)node * 64;
            rbE[rt] = efeat + (size_t)e * 64;
        } else {
            rbN[rt] = ((row < 64) ? featS : featD) + (size_t)e * 128;
            rbE[rt] = nullptr;
        }
    }

    f32x4 acc[2][8] = {};

    // ---- chunks 0..3: feature half (k = 0..127) ----
#pragma unroll
    for (int ch = 0; ch < 4; ++ch) {
        const int koff = ch * 32 + kgrp * 8;
        short8v Ah[2], Al[2];
#pragma unroll
        for (int rt = 0; rt < 2; ++rt) {
            const float* p;
            if (LAYER == 1) {
                // ch 0,1 -> nfeat half (k<64); ch 2,3 -> efeat half (k>=64)
                p = (ch < 2) ? (rbN[rt] + koff) : (rbE[rt] + (koff - 64));
            } else {
                p = rbN[rt] + koff;
            }
            float4 x0 = *(const float4*)p;
            float4 x1 = *(const float4*)(p + 4);
            split8(x0, x1, &Ah[rt], &Al[rt]);
        }
#pragma unroll
        for (int ct = 0; ct < 8; ++ct) {
            int c = ct * 16 + krow;
            short8v Bh = *(const short8v*)(WtH + (size_t)c * 192 + koff);
            short8v Bl = *(const short8v*)(WtL + (size_t)c * 192 + koff);
#pragma unroll
            for (int rt = 0; rt < 2; ++rt) {
                acc[rt][ct] = __builtin_amdgcn_mfma_f32_16x16x32_bf16(Ah[rt], Bh, acc[rt][ct], 0, 0, 0);
                acc[rt][ct] = __builtin_amdgcn_mfma_f32_16x16x32_bf16(Ah[rt], Bl, acc[rt][ct], 0, 0, 0);
                acc[rt][ct] = __builtin_amdgcn_mfma_f32_16x16x32_bf16(Al[rt], Bh, acc[rt][ct], 0, 0, 0);
            }
        }
    }

    // ---- chunks 4..5: time-encoding half (k = 128..191) ----
#pragma unroll
    for (int ch = 4; ch < 6; ++ch) {
        const int koff = ch * 32 + kgrp * 8;
        const int kt = koff - 128;
        short8v Ah[2], Al[2];
#pragma unroll
        for (int rt = 0; rt < 2; ++rt) {
            int el = (w * 32 + rt * 16 + krow) & 63;   // src & dst share te
            Ah[rt] = *(const short8v*)&teH[el][kt];
            Al[rt] = *(const short8v*)&teL[el][kt];
        }
#pragma unroll
        for (int ct = 0; ct < 8; ++ct) {
            int c = ct * 16 + krow;
            short8v Bh = *(const short8v*)(WtH + (size_t)c * 192 + koff);
            short8v Bl = *(const short8v*)(WtL + (size_t)c * 192 + koff);
#pragma unroll
            for (int rt = 0; rt < 2; ++rt) {
                acc[rt][ct] = __builtin_amdgcn_mfma_f32_16x16x32_bf16(Ah[rt], Bh, acc[rt][ct], 0, 0, 0);
                acc[rt][ct] = __builtin_amdgcn_mfma_f32_16x16x32_bf16(Ah[rt], Bl, acc[rt][ct], 0, 0, 0);
                acc[rt][ct] = __builtin_amdgcn_mfma_f32_16x16x32_bf16(Al[rt], Bh, acc[rt][ct], 0, 0, 0);
            }
        }
    }

    // ---- epilogue: + b_self + neigh_proj[endpoint], relu, store in place ----
    float bcol[8];
#pragma unroll
    for (int ct = 0; ct < 8; ++ct) bcol[ct] = bias[ct * 16 + krow];
#pragma unroll
    for (int rt = 0; rt < 2; ++rt) {
#pragma unroll
        for (int j = 0; j < 4; ++j) {
            int row = w * 32 + rt * 16 + kgrp * 4 + j;
            int e = e0 + (row & 63);
            if (e < EE) {
                bool isS = row < 64;
                int node = isS ? src[e] : dst[e];
                const float* np = neigh + (size_t)node * 128;
                float* op = (isS ? outS : outD) + (size_t)e * 128;
#pragma unroll
                for (int ct = 0; ct < 8; ++ct) {
                    float v2 = acc[rt][ct][j] + bcol[ct] + np[ct * 16 + krow];
                    op[ct * 16 + krow] = fmaxf(v2, 0.f);
                }
            }
        }
    }
}

// ---------------------------------------------------------------------------
extern "C" void kernel_launch(void* const* d_in, const int* in_sizes, int n_in,
                              void* d_out, int out_size, void* d_ws, size_t ws_size,
                              hipStream_t stream) {
    const float* nfeat = (const float*)d_in[0];
    const float* efeat = (const float*)d_in[1];
    const int*   src   = (const int*)d_in[2];
    const int*   dst   = (const int*)d_in[3];
    const float* ts    = (const float*)d_in[4];
    const float* Wself[2]  = {(const float*)d_in[5],  (const float*)d_in[11]};
    const float* bself[2]  = {(const float*)d_in[6],  (const float*)d_in[12]};
    const float* Wneigh[2] = {(const float*)d_in[7],  (const float*)d_in[13]};
    const float* bneigh[2] = {(const float*)d_in[8],  (const float*)d_in[14]};
    const float* omega[2]  = {(const float*)d_in[9],  (const float*)d_in[15]};
    const float* phase[2]  = {(const float*)d_in[10], (const float*)d_in[16]};

    // d_out doubles as the edge-feature ping-pong storage (in-place layer 2).
    float* outS = (float*)d_out;                   // src_feat  [E,128]
    float* outD = outS + (size_t)EE * 128;         // dst_feat  [E,128]

    // workspace: mean | neigh | pos | eidx | split-bf16 weights (~128.8 MB)
    float* mean  = (float*)d_ws;
    float* neigh = mean + (size_t)NN * 128;
    int*   pos   = (int*)(neigh + (size_t)NN * 128);
    int*   eidx  = pos + NN;
    unsigned short* wb = (unsigned short*)(eidx + (size_t)NN * CAP);
    unsigned short* WsH[2] = {wb,                 wb + 2 * 128 * 192};
    unsigned short* WsL[2] = {wb + 128 * 192,     wb + 3 * 128 * 192};
    unsigned short* wn = wb + 4 * 128 * 192;
    unsigned short* WnH[2] = {wn,                 wn + 2 * 128 * 128};
    unsigned short* WnL[2] = {wn + 128 * 128,     wn + 3 * 128 * 128};

    hipMemsetAsync(pos, 0, NN * sizeof(int), stream);
    k_build<<<(EE + 255) / 256, 256, 0, stream>>>(src, dst, pos, eidx);
    for (int l = 0; l < 2; ++l) {
        k_wt<<<(192 * 128 + 255) / 256, 256, 0, stream>>>(Wself[l], 192, WsH[l], WsL[l]);
        k_wt<<<(128 * 128 + 255) / 256, 256, 0, stream>>>(Wneigh[l], 128, WnH[l], WnL[l]);
    }

    // ---- layer 1 (A gathered straight from nfeat/efeat; no combine pass) ----
    k_agg<1><<<(NN * 64 + 255) / 256, 256, 0, stream>>>(outS, outD, nfeat, efeat,
                                                        src, dst, pos, eidx, mean);
    k_neigh_mfma<<<(NN + 127) / 128, 256, 0, stream>>>(mean, WnH[0], WnL[0], bneigh[0], neigh);
    k_edge_mfma<1><<<(EE + 63) / 64, 256, 0, stream>>>(outS, outD, nfeat, efeat,
                                                       outS, outD, src, dst, ts,
                                                       WsH[0], WsL[0], bself[0], neigh,
                                                       omega[0], phase[0]);

    // ---- layer 2 (ping-pong rows, in place) ----
    k_agg<2><<<(NN * 64 + 255) / 256, 256, 0, stream>>>(outS, outD, nfeat, efeat,
                                                        src, dst, pos, eidx, mean);
    k_neigh_mfma<<<(NN + 127) / 128, 256, 0, stream>>>(mean, WnH[1], WnL[1], bneigh[1], neigh);
    k_edge_mfma<2><<<(EE + 63) / 64, 256, 0, stream>>>(outS, outD, nfeat, efeat,
                                                       outS, outD, src, dst, ts,
                                                       WsH[1], WsL[1], bself[1], neigh,
                                                       omega[1], phase[1]);
}

// Round 3
// 1913.328 us; speedup vs baseline: 1.1185x; 1.1088x over previous
//
#include <hip/hip_runtime.h>
#include <cstdint>
#include <cmath>

// Problem constants (match reference)
#define NN 100000   // nodes
#define EE 500000   // edges
// DN=64, DE=64, D=128, TD=64, K_self = 192
#define CAP 48      // incidence capacity/node (deg ~ Poisson(10): P(>=48) ~ 1e-20)

typedef __attribute__((ext_vector_type(8))) short short8v;   // 8 bf16 (4 VGPRs)
typedef __attribute__((ext_vector_type(4))) float f32x4;     // MFMA accumulator

// float -> bf16 round-to-nearest-even (bit trick; inputs finite)
static __device__ __forceinline__ unsigned short f2bf_rne(float x) {
    unsigned u = __float_as_uint(x);
    u += 0x7FFFu + ((u >> 16) & 1u);
    return (unsigned short)(u >> 16);
}

// pack 8 consecutive floats into hi/lo bf16 vectors (hi=truncate, lo=RNE residual)
static __device__ __forceinline__ void split8(float4 a, float4 b,
                                              short8v* hi, short8v* lo) {
    union { short8v v; unsigned u[4]; } H, L;
    float f[8] = {a.x, a.y, a.z, a.w, b.x, b.y, b.z, b.w};
#pragma unroll
    for (int p = 0; p < 4; ++p) {
        unsigned u0 = __float_as_uint(f[2 * p]);
        unsigned u1 = __float_as_uint(f[2 * p + 1]);
        H.u[p] = (u0 >> 16) | (u1 & 0xFFFF0000u);
        float r0 = f[2 * p]     - __uint_as_float(u0 & 0xFFFF0000u);
        float r1 = f[2 * p + 1] - __uint_as_float(u1 & 0xFFFF0000u);
        L.u[p] = (unsigned)f2bf_rne(r0) | ((unsigned)f2bf_rne(r1) << 16);
    }
    *hi = H.v; *lo = L.v;
}

// async 16B global->LDS (dest: wave-uniform base + lane*16; src: per-lane)
static __device__ __forceinline__ void lds_dma16(const void* g, void* l) {
    __builtin_amdgcn_global_load_lds(
        (const __attribute__((address_space(1))) unsigned int*)g,
        (__attribute__((address_space(3))) unsigned int*)l, 16, 0, 0);
}

// ---------------------------------------------------------------------------
// Build per-node incidence lists: entry = {(e<<1)|side, other_node}.
// side=1 -> node is src (contribution = dst-side row e); side=0 -> node is dst.
__global__ __launch_bounds__(256) void k_build(const int* __restrict__ src,
                                               const int* __restrict__ dst,
                                               int* __restrict__ pos,
                                               int2* __restrict__ inc) {
    int e = blockIdx.x * 256 + threadIdx.x;
    if (e >= EE) return;
    int s = src[e], d = dst[e];
    int sl = atomicAdd(&pos[s], 1);
    if (sl < CAP) inc[(size_t)s * CAP + sl] = make_int2((e << 1) | 1, d);
    int dl = atomicAdd(&pos[d], 1);
    if (dl < CAP) inc[(size_t)d * CAP + dl] = make_int2((e << 1), s);
}

// ---------------------------------------------------------------------------
// Weight prep: W [K][128] fp32 row-major -> transposed split-bf16 H/L [128][K].
__global__ __launch_bounds__(256) void k_wt(const float* __restrict__ W, int K,
                                            unsigned short* __restrict__ H,
                                            unsigned short* __restrict__ L) {
    int idx = blockIdx.x * 256 + threadIdx.x;
    if (idx >= K * 128) return;
    int k = idx >> 7, c = idx & 127;
    float x = W[idx];
    unsigned u = __float_as_uint(x);
    H[(size_t)c * K + k] = (unsigned short)(u >> 16);
    float r = x - __uint_as_float(u & 0xFFFF0000u);
    L[(size_t)c * K + k] = f2bf_rne(r);
}

// ---------------------------------------------------------------------------
// Aggregation: one wave per node, quarter-wave (16 lanes x 32B) per entry ->
// 4 rows in flight.  LAYER1 gathers [nfeat[other], efeat[e]] (other comes from
// the incidence entry, no dependent hop); LAYER2 gathers ping-pong rows.
template <int LAYER>
__global__ __launch_bounds__(256) void k_agg(const float* __restrict__ featS,
                                             const float* __restrict__ featD,
                                             const float* __restrict__ nfeat,
                                             const float* __restrict__ efeat,
                                             const int* __restrict__ pos,
                                             const int2* __restrict__ inc,
                                             float* __restrict__ mean) {
    int w = (blockIdx.x * 256 + threadIdx.x) >> 6;   // node id
    int lane = threadIdx.x & 63;
    if (w >= NN) return;
    int q = lane >> 4, cl = lane & 15;               // channels cl*8 .. cl*8+7
    int d = pos[w];
    int dd = min(d, CAP);
    const int2* lst = inc + (size_t)w * CAP;
    float a0 = 0.f, a1 = 0.f, a2 = 0.f, a3 = 0.f;
    float a4 = 0.f, a5 = 0.f, a6 = 0.f, a7 = 0.f;
    for (int j = q; j < dd; j += 4) {
        int2 en = lst[j];
        int e = en.x >> 1, side = en.x & 1;
        const float* p;
        if (LAYER == 1) {
            p = (cl < 8) ? (nfeat + (size_t)en.y * 64 + cl * 8)
                         : (efeat + (size_t)e * 64 + (cl - 8) * 8);
        } else {
            p = (side ? featD : featS) + (size_t)e * 128 + cl * 8;
        }
        float4 v0 = *(const float4*)p;
        float4 v1 = *(const float4*)(p + 4);
        a0 += v0.x; a1 += v0.y; a2 += v0.z; a3 += v0.w;
        a4 += v1.x; a5 += v1.y; a6 += v1.z; a7 += v1.w;
    }
    // combine the 4 quarter-wave partial sums (lanes same cl differ in bits 4,5)
#pragma unroll
    for (int m = 16; m <= 32; m <<= 1) {
        a0 += __shfl_xor(a0, m); a1 += __shfl_xor(a1, m);
        a2 += __shfl_xor(a2, m); a3 += __shfl_xor(a3, m);
        a4 += __shfl_xor(a4, m); a5 += __shfl_xor(a5, m);
        a6 += __shfl_xor(a6, m); a7 += __shfl_xor(a7, m);
    }
    if (q == 0) {
        float inv = 1.0f / fmaxf((float)d, 1.0f);
        float4 r0, r1;
        r0.x = a0 * inv; r0.y = a1 * inv; r0.z = a2 * inv; r0.w = a3 * inv;
        r1.x = a4 * inv; r1.y = a5 * inv; r1.z = a6 * inv; r1.w = a7 * inv;
        *(float4*)(mean + (size_t)w * 128 + cl * 8) = r0;
        *(float4*)(mean + (size_t)w * 128 + cl * 8 + 4) = r1;
    }
}

// ---------------------------------------------------------------------------
// neigh_proj = mean @ W_neigh + b_neigh.  Waves split (2 row-grp x 2 col-grp):
// each wave 64 rows x 64 cols (rt=4, ct=4); B loads batched 8/chunk.
__global__ __launch_bounds__(256) void k_neigh_mfma(
        const float* __restrict__ mean,
        const unsigned short* __restrict__ WtH,   // [128 cols][128 k] bf16 hi
        const unsigned short* __restrict__ WtL,   // lo
        const float* __restrict__ bias,
        float* __restrict__ outp) {
    const int tid  = threadIdx.x;
    const int n0   = blockIdx.x * 128;
    const int lane = tid & 63;
    const int w    = tid >> 6;
    const int wr   = w >> 1, wc = w & 1;
    const int krow = lane & 15;
    const int kgrp = lane >> 4;

    const float* rb[4];
#pragma unroll
    for (int rt = 0; rt < 4; ++rt) {
        int n = min(n0 + wr * 64 + rt * 16 + krow, NN - 1);
        rb[rt] = mean + (size_t)n * 128;
    }

    f32x4 acc[4][4] = {};
#pragma unroll
    for (int ch = 0; ch < 4; ++ch) {
        const int koff = ch * 32 + kgrp * 8;
        short8v Ah[4], Al[4];
#pragma unroll
        for (int rt = 0; rt < 4; ++rt) {
            float4 x0 = *(const float4*)(rb[rt] + koff);
            float4 x1 = *(const float4*)(rb[rt] + koff + 4);
            split8(x0, x1, &Ah[rt], &Al[rt]);
        }
        short8v Bh[4], Bl[4];
#pragma unroll
        for (int ct = 0; ct < 4; ++ct) {
            int c = wc * 64 + ct * 16 + krow;
            Bh[ct] = *(const short8v*)(WtH + (size_t)c * 128 + koff);
            Bl[ct] = *(const short8v*)(WtL + (size_t)c * 128 + koff);
        }
#pragma unroll
        for (int ct = 0; ct < 4; ++ct)
#pragma unroll
            for (int rt = 0; rt < 4; ++rt) {
                acc[rt][ct] = __builtin_amdgcn_mfma_f32_16x16x32_bf16(Ah[rt], Bh[ct], acc[rt][ct], 0, 0, 0);
                acc[rt][ct] = __builtin_amdgcn_mfma_f32_16x16x32_bf16(Ah[rt], Bl[ct], acc[rt][ct], 0, 0, 0);
                acc[rt][ct] = __builtin_amdgcn_mfma_f32_16x16x32_bf16(Al[rt], Bh[ct], acc[rt][ct], 0, 0, 0);
            }
    }

    float bcol[4];
#pragma unroll
    for (int ct = 0; ct < 4; ++ct) bcol[ct] = bias[wc * 64 + ct * 16 + krow];
#pragma unroll
    for (int rt = 0; rt < 4; ++rt)
#pragma unroll
        for (int j = 0; j < 4; ++j) {
            int n = n0 + wr * 64 + rt * 16 + kgrp * 4 + j;
            if (n < NN) {
                float* op = outp + (size_t)n * 128;
#pragma unroll
                for (int ct = 0; ct < 4; ++ct)
                    op[wc * 64 + ct * 16 + krow] = acc[rt][ct][j] + bcol[ct];
            }
        }
}

// ---------------------------------------------------------------------------
// Edge update via split-bf16 MFMA with async-DMA A staging.
// Block = 64 edges -> 128 rows (0-63 src side, 64-127 dst side) x 128 cols.
// 4 waves: (wr,wc) in 2x2 -> each wave 64 rows x 64 cols (rt=4, ct=4).
// K=192: chunks 0-3 = feature half, A staged fp32 via global_load_lds
// (double-buffered, 1 barrier/chunk, bank-rotated slots); chunks 4-5 = te LDS.
// B fragments direct from global bf16 (L2-hot), batched 8 loads/chunk.
template <int LAYER>
__global__ __launch_bounds__(256) void k_edge_mfma(
        const float* __restrict__ featS, const float* __restrict__ featD,
        const float* __restrict__ nfeat, const float* __restrict__ efeat,
        float* __restrict__ outS, float* __restrict__ outD,
        const int* __restrict__ src, const int* __restrict__ dst,
        const float* __restrict__ ts,
        const unsigned short* __restrict__ WtH,   // [128 cols][192 k] bf16 hi
        const unsigned short* __restrict__ WtL,   // lo
        const float* __restrict__ bias,
        const float* __restrict__ neigh,
        const float* __restrict__ omega, const float* __restrict__ phase) {
    __shared__ float Abuf[2][128][32];        // 2 x 16 KB, bank-rotated slots
    __shared__ unsigned short teH[64][72];    // stride 72 shorts -> 2-way alias
    __shared__ unsigned short teL[64][72];

    const int tid  = threadIdx.x;
    const int e0   = blockIdx.x * 64;
    const int lane = tid & 63;
    const int w    = tid >> 6;
    const int wr   = w >> 1, wc = w & 1;
    const int krow = lane & 15;
    const int kgrp = lane >> 4;

    // ---- time encoding: 64 edges x 64 td, split hi/lo bf16 ----
    {
        const int tl = tid & 63;
        const int j0 = (tid >> 6) * 16;
        const float tval = ts[min(e0 + tl, EE - 1)];
#pragma unroll
        for (int j = 0; j < 16; j += 2) {
            int jj = j0 + j;
            float c0 = cosf(fmaf(tval, omega[jj],     phase[jj]));
            float c1 = cosf(fmaf(tval, omega[jj + 1], phase[jj + 1]));
            unsigned u0 = __float_as_uint(c0), u1 = __float_as_uint(c1);
            *(unsigned*)&teH[tl][jj] = (u0 >> 16) | (u1 & 0xFFFF0000u);
            float r0 = c0 - __uint_as_float(u0 & 0xFFFF0000u);
            float r1 = c1 - __uint_as_float(u1 & 0xFFFF0000u);
            *(unsigned*)&teL[tl][jj] =
                (unsigned)f2bf_rne(r0) | ((unsigned)f2bf_rne(r1) << 16);
        }
    }

    // ---- DMA row assignment: issue q handles rows w*32+q*8 .. +8 ----
    // thread -> row w*32+q*8+(lane>>3), LDS slot p_slot=lane&7; fetches global
    // part p_g = (p_slot - row)&7  (bank rotation, inverted on the source).
    const float* gbN[4];   // LAYER1: nfeat[endpoint] row ; LAYER2: feat row
    const float* gbE[4];   // LAYER1: efeat row
#pragma unroll
    for (int qq = 0; qq < 4; ++qq) {
        int row = w * 32 + qq * 8 + (lane >> 3);
        int e = min(e0 + (row & 63), EE - 1);
        if (LAYER == 1) {
            int node = (row < 64) ? src[e] : dst[e];
            gbN[qq] = nfeat + (size_t)node * 64;
            gbE[qq] = efeat + (size_t)e * 64;
        } else {
            gbN[qq] = ((row < 64) ? featS : featD) + (size_t)e * 128;
            gbE[qq] = nullptr;
        }
    }
    const int pslot = lane & 7;

    auto dma_chunk = [&](int b, int ch) {
#pragma unroll
        for (int qq = 0; qq < 4; ++qq) {
            int row = w * 32 + qq * 8 + (lane >> 3);
            int pg = (pslot - row) & 7;
            const float* gsrc;
            if (LAYER == 1)
                gsrc = ((ch < 2) ? (gbN[qq] + ch * 32) : (gbE[qq] + (ch - 2) * 32)) + pg * 4;
            else
                gsrc = gbN[qq] + ch * 32 + pg * 4;
            lds_dma16(gsrc, &Abuf[b][(w * 4 + qq) * 8][0]);   // wave-uniform dest
        }
    };

    f32x4 acc[4][4] = {};
    dma_chunk(0, 0);

    // ---- chunks 0..3: feature half ----
#pragma unroll
    for (int ch = 0; ch < 4; ++ch) {
        __syncthreads();                  // drains DMA(ch) (implicit vmcnt(0))
        if (ch < 3) dma_chunk((ch + 1) & 1, ch + 1);
        const int b = ch & 1;
        const int koff = ch * 32 + kgrp * 8;
        short8v Ah[4], Al[4];
#pragma unroll
        for (int rt = 0; rt < 4; ++rt) {
            int row = wr * 64 + rt * 16 + krow;
            float4 x0 = *(const float4*)&Abuf[b][row][(((2 * kgrp)     + row) & 7) * 4];
            float4 x1 = *(const float4*)&Abuf[b][row][(((2 * kgrp + 1) + row) & 7) * 4];
            split8(x0, x1, &Ah[rt], &Al[rt]);
        }
        short8v Bh[4], Bl[4];
#pragma unroll
        for (int ct = 0; ct < 4; ++ct) {
            int c = wc * 64 + ct * 16 + krow;
            Bh[ct] = *(const short8v*)(WtH + (size_t)c * 192 + koff);
            Bl[ct] = *(const short8v*)(WtL + (size_t)c * 192 + koff);
        }
#pragma unroll
        for (int ct = 0; ct < 4; ++ct)
#pragma unroll
            for (int rt = 0; rt < 4; ++rt) {
                acc[rt][ct] = __builtin_amdgcn_mfma_f32_16x16x32_bf16(Ah[rt], Bh[ct], acc[rt][ct], 0, 0, 0);
                acc[rt][ct] = __builtin_amdgcn_mfma_f32_16x16x32_bf16(Ah[rt], Bl[ct], acc[rt][ct], 0, 0, 0);
                acc[rt][ct] = __builtin_amdgcn_mfma_f32_16x16x32_bf16(Al[rt], Bh[ct], acc[rt][ct], 0, 0, 0);
            }
    }

    // ---- chunks 4..5: time-encoding half (te synced by earlier barriers) ----
#pragma unroll
    for (int ch = 4; ch < 6; ++ch) {
        const int koff = ch * 32 + kgrp * 8;
        const int kt = koff - 128;
        short8v Ah[4], Al[4];
#pragma unroll
        for (int rt = 0; rt < 4; ++rt) {
            int el = rt * 16 + krow;                  // src & dst share te
            Ah[rt] = *(const short8v*)&teH[el][kt];
            Al[rt] = *(const short8v*)&teL[el][kt];
        }
        short8v Bh[4], Bl[4];
#pragma unroll
        for (int ct = 0; ct < 4; ++ct) {
            int c = wc * 64 + ct * 16 + krow;
            Bh[ct] = *(const short8v*)(WtH + (size_t)c * 192 + koff);
            Bl[ct] = *(const short8v*)(WtL + (size_t)c * 192 + koff);
        }
#pragma unroll
        for (int ct = 0; ct < 4; ++ct)
#pragma unroll
            for (int rt = 0; rt < 4; ++rt) {
                acc[rt][ct] = __builtin_amdgcn_mfma_f32_16x16x32_bf16(Ah[rt], Bh[ct], acc[rt][ct], 0, 0, 0);
                acc[rt][ct] = __builtin_amdgcn_mfma_f32_16x16x32_bf16(Ah[rt], Bl[ct], acc[rt][ct], 0, 0, 0);
                acc[rt][ct] = __builtin_amdgcn_mfma_f32_16x16x32_bf16(Al[rt], Bh[ct], acc[rt][ct], 0, 0, 0);
            }
    }

    // ---- epilogue: + b_self + neigh_proj[endpoint], relu, store in place ----
    float bcol[4];
#pragma unroll
    for (int ct = 0; ct < 4; ++ct) bcol[ct] = bias[wc * 64 + ct * 16 + krow];
#pragma unroll
    for (int rt = 0; rt < 4; ++rt)
#pragma unroll
        for (int j = 0; j < 4; ++j) {
            int row = wr * 64 + rt * 16 + kgrp * 4 + j;
            int e = e0 + (row & 63);
            if (e < EE) {
                bool isS = row < 64;
                int node = isS ? src[e] : dst[e];
                const float* np = neigh + (size_t)node * 128;
                float* op = (isS ? outS : outD) + (size_t)e * 128;
#pragma unroll
                for (int ct = 0; ct < 4; ++ct) {
                    int col = wc * 64 + ct * 16 + krow;
                    float v2 = acc[rt][ct][j] + bcol[ct] + np[col];
                    op[col] = fmaxf(v2, 0.f);
                }
            }
        }
}

// ---------------------------------------------------------------------------
extern "C" void kernel_launch(void* const* d_in, const int* in_sizes, int n_in,
                              void* d_out, int out_size, void* d_ws, size_t ws_size,
                              hipStream_t stream) {
    const float* nfeat = (const float*)d_in[0];
    const float* efeat = (const float*)d_in[1];
    const int*   src   = (const int*)d_in[2];
    const int*   dst   = (const int*)d_in[3];
    const float* ts    = (const float*)d_in[4];
    const float* Wself[2]  = {(const float*)d_in[5],  (const float*)d_in[11]};
    const float* bself[2]  = {(const float*)d_in[6],  (const float*)d_in[12]};
    const float* Wneigh[2] = {(const float*)d_in[7],  (const float*)d_in[13]};
    const float* bneigh[2] = {(const float*)d_in[8],  (const float*)d_in[14]};
    const float* omega[2]  = {(const float*)d_in[9],  (const float*)d_in[15]};
    const float* phase[2]  = {(const float*)d_in[10], (const float*)d_in[16]};

    // d_out doubles as the edge-feature ping-pong storage (in-place layer 2).
    float* outS = (float*)d_out;                   // src_feat  [E,128]
    float* outD = outS + (size_t)EE * 128;         // dst_feat  [E,128]

    // workspace: mean | neigh | pos | inc | split-bf16 weights (~141.5 MB)
    float* mean  = (float*)d_ws;
    float* neigh = mean + (size_t)NN * 128;
    int*   pos   = (int*)(neigh + (size_t)NN * 128);
    int2*  inc   = (int2*)(pos + NN);
    unsigned short* wb = (unsigned short*)(inc + (size_t)NN * CAP);
    unsigned short* WsH[2] = {wb,                 wb + 2 * 128 * 192};
    unsigned short* WsL[2] = {wb + 128 * 192,     wb + 3 * 128 * 192};
    unsigned short* wn = wb + 4 * 128 * 192;
    unsigned short* WnH[2] = {wn,                 wn + 2 * 128 * 128};
    unsigned short* WnL[2] = {wn + 128 * 128,     wn + 3 * 128 * 128};

    hipMemsetAsync(pos, 0, NN * sizeof(int), stream);
    k_build<<<(EE + 255) / 256, 256, 0, stream>>>(src, dst, pos, inc);
    for (int l = 0; l < 2; ++l) {
        k_wt<<<(192 * 128 + 255) / 256, 256, 0, stream>>>(Wself[l], 192, WsH[l], WsL[l]);
        k_wt<<<(128 * 128 + 255) / 256, 256, 0, stream>>>(Wneigh[l], 128, WnH[l], WnL[l]);
    }

    // ---- layer 1 (A gathered straight from nfeat/efeat; no combine pass) ----
    k_agg<1><<<(NN * 64 + 255) / 256, 256, 0, stream>>>(outS, outD, nfeat, efeat,
                                                        pos, inc, mean);
    k_neigh_mfma<<<(NN + 127) / 128, 256, 0, stream>>>(mean, WnH[0], WnL[0], bneigh[0], neigh);
    k_edge_mfma<1><<<(EE + 63) / 64, 256, 0, stream>>>(outS, outD, nfeat, efeat,
                                                       outS, outD, src, dst, ts,
                                                       WsH[0], WsL[0], bself[0], neigh,
                                                       omega[0], phase[0]);

    // ---- layer 2 (ping-pong rows, in place) ----
    k_agg<2><<<(NN * 64 + 255) / 256, 256, 0, stream>>>(outS, outD, nfeat, efeat,
                                                        pos, inc, mean);
    k_neigh_mfma<<<(NN + 127) / 128, 256, 0, stream>>>(mean, WnH[1], WnL[1], bneigh[1], neigh);
    k_edge_mfma<2><<<(EE + 63) / 64, 256, 0, stream>>>(outS, outD, nfeat, efeat,
                                                       outS, outD, src, dst, ts,
                                                       WsH[1], WsL[1], bself[1], neigh,
                                                       omega[1], phase[1]);
}

// Round 4
// 1854.180 us; speedup vs baseline: 1.1542x; 1.0319x over previous
//
#include <hip/hip_runtime.h>
#include <cstdint>
#include <cmath>

// Problem constants (match reference)
#define NN 100000   // nodes
#define EE 500000   // edges
// DN=64, DE=64, D=128, TD=64.  Fused K = 192 (self) + 128 (neigh) = 320.
#define CAP 48      // incidence capacity/node (deg ~ Poisson(10): P(>=48) ~ 1e-20)

typedef __attribute__((ext_vector_type(8))) short short8v;   // 8 bf16 (4 VGPRs)
typedef __attribute__((ext_vector_type(4))) float f32x4;     // MFMA accumulator

// float -> bf16 round-to-nearest-even (bit trick; inputs finite)
static __device__ __forceinline__ unsigned short f2bf_rne(float x) {
    unsigned u = __float_as_uint(x);
    u += 0x7FFFu + ((u >> 16) & 1u);
    return (unsigned short)(u >> 16);
}

// pack 8 consecutive floats into hi/lo bf16 vectors (hi=truncate, lo=RNE residual)
static __device__ __forceinline__ void split8(float4 a, float4 b,
                                              short8v* hi, short8v* lo) {
    union { short8v v; unsigned u[4]; } H, L;
    float f[8] = {a.x, a.y, a.z, a.w, b.x, b.y, b.z, b.w};
#pragma unroll
    for (int p = 0; p < 4; ++p) {
        unsigned u0 = __float_as_uint(f[2 * p]);
        unsigned u1 = __float_as_uint(f[2 * p + 1]);
        H.u[p] = (u0 >> 16) | (u1 & 0xFFFF0000u);
        float r0 = f[2 * p]     - __uint_as_float(u0 & 0xFFFF0000u);
        float r1 = f[2 * p + 1] - __uint_as_float(u1 & 0xFFFF0000u);
        L.u[p] = (unsigned)f2bf_rne(r0) | ((unsigned)f2bf_rne(r1) << 16);
    }
    *hi = H.v; *lo = L.v;
}

// async 16B global->LDS (dest: wave-uniform base + lane*16; src: per-lane)
static __device__ __forceinline__ void lds_dma16(const void* g, void* l) {
    __builtin_amdgcn_global_load_lds(
        (const __attribute__((address_space(1))) unsigned int*)g,
        (__attribute__((address_space(3))) unsigned int*)l, 16, 0, 0);
}

// ---------------------------------------------------------------------------
// Build per-node incidence lists: entry = {(e<<1)|side, other_node}.
__global__ __launch_bounds__(256) void k_build(const int* __restrict__ src,
                                               const int* __restrict__ dst,
                                               int* __restrict__ pos,
                                               int2* __restrict__ inc) {
    int e = blockIdx.x * 256 + threadIdx.x;
    if (e >= EE) return;
    int s = src[e], d = dst[e];
    int sl = atomicAdd(&pos[s], 1);
    if (sl < CAP) inc[(size_t)s * CAP + sl] = make_int2((e << 1) | 1, d);
    int dl = atomicAdd(&pos[d], 1);
    if (dl < CAP) inc[(size_t)d * CAP + dl] = make_int2((e << 1), s);
}

// ---------------------------------------------------------------------------
// Fused-weight prep: rows 0..191 = W_self [192][128], rows 192..319 = W_neigh
// [128][128]; output transposed split-bf16 H/L [128 cols][320 k].
__global__ __launch_bounds__(256) void k_wt2(const float* __restrict__ Wself,
                                             const float* __restrict__ Wneigh,
                                             unsigned short* __restrict__ H,
                                             unsigned short* __restrict__ L) {
    int idx = blockIdx.x * 256 + threadIdx.x;
    if (idx >= 320 * 128) return;
    int k = idx >> 7, c = idx & 127;
    float x = (k < 192) ? Wself[k * 128 + c] : Wneigh[(k - 192) * 128 + c];
    unsigned u = __float_as_uint(x);
    H[(size_t)c * 320 + k] = (unsigned short)(u >> 16);
    float r = x - __uint_as_float(u & 0xFFFF0000u);
    L[(size_t)c * 320 + k] = f2bf_rne(r);
}

// ---------------------------------------------------------------------------
// Aggregation: one wave per node, quarter-wave (16 lanes x 32B) per entry,
// +1-deep entry prefetch.  LAYER1 gathers [nfeat[other], efeat[e]]; LAYER2
// gathers ping-pong rows.
template <int LAYER>
__global__ __launch_bounds__(256) void k_agg(const float* __restrict__ featS,
                                             const float* __restrict__ featD,
                                             const float* __restrict__ nfeat,
                                             const float* __restrict__ efeat,
                                             const int* __restrict__ pos,
                                             const int2* __restrict__ inc,
                                             float* __restrict__ mean) {
    int w = (blockIdx.x * 256 + threadIdx.x) >> 6;   // node id
    int lane = threadIdx.x & 63;
    if (w >= NN) return;
    int q = lane >> 4, cl = lane & 15;               // channels cl*8 .. cl*8+7
    int d = pos[w];
    int dd = min(d, CAP);
    const int2* lst = inc + (size_t)w * CAP;
    float a0 = 0.f, a1 = 0.f, a2 = 0.f, a3 = 0.f;
    float a4 = 0.f, a5 = 0.f, a6 = 0.f, a7 = 0.f;
    int2 en = (q < dd) ? lst[q] : make_int2(0, 0);
    for (int j = q; j < dd; j += 4) {
        int2 nxt = (j + 4 < dd) ? lst[j + 4] : en;   // prefetch next entry
        int e = en.x >> 1, side = en.x & 1;
        const float* p;
        if (LAYER == 1) {
            p = (cl < 8) ? (nfeat + (size_t)en.y * 64 + cl * 8)
                         : (efeat + (size_t)e * 64 + (cl - 8) * 8);
        } else {
            p = (side ? featD : featS) + (size_t)e * 128 + cl * 8;
        }
        float4 v0 = *(const float4*)p;
        float4 v1 = *(const float4*)(p + 4);
        a0 += v0.x; a1 += v0.y; a2 += v0.z; a3 += v0.w;
        a4 += v1.x; a5 += v1.y; a6 += v1.z; a7 += v1.w;
        en = nxt;
    }
#pragma unroll
    for (int m = 16; m <= 32; m <<= 1) {
        a0 += __shfl_xor(a0, m); a1 += __shfl_xor(a1, m);
        a2 += __shfl_xor(a2, m); a3 += __shfl_xor(a3, m);
        a4 += __shfl_xor(a4, m); a5 += __shfl_xor(a5, m);
        a6 += __shfl_xor(a6, m); a7 += __shfl_xor(a7, m);
    }
    if (q == 0) {
        float inv = 1.0f / fmaxf((float)d, 1.0f);
        float4 r0, r1;
        r0.x = a0 * inv; r0.y = a1 * inv; r0.z = a2 * inv; r0.w = a3 * inv;
        r1.x = a4 * inv; r1.y = a5 * inv; r1.z = a6 * inv; r1.w = a7 * inv;
        *(float4*)(mean + (size_t)w * 128 + cl * 8) = r0;
        *(float4*)(mean + (size_t)w * 128 + cl * 8 + 4) = r1;
    }
}

// ---------------------------------------------------------------------------
// Fused edge update: out = relu(concat(prev, te, mean[endpoint]) @ Wcat + b).
// Block = 64 edges -> 128 rows (0-63 src side) x 128 cols; 4 waves (2x2), each
// 64 rows x 64 cols (rt=4, ct=4), split-bf16 MFMA (3 terms).
// K = 320 in 10 chunks of 32: DMA chunks j=0..7 (k = {0,32,64,96} feat,
// {192,224,256,288} mean-gather), te chunks k = {128,160} from LDS at the end.
// Pipeline: 3 LDS A-buffers, DMA issued 2 chunks ahead, raw s_barrier +
// counted vmcnt(4) (never 0 in the loop).  In-order vmcnt retirement: draining
// B(j) implies DMA(j+1) drained; DMA(j+2) stays in flight across the barrier.
template <int LAYER>
__global__ __launch_bounds__(256) void k_edge_fused(
        const float* __restrict__ featS, const float* __restrict__ featD,
        const float* __restrict__ nfeat, const float* __restrict__ efeat,
        const float* __restrict__ mean,
        float* __restrict__ outS, float* __restrict__ outD,
        const int* __restrict__ src, const int* __restrict__ dst,
        const float* __restrict__ ts,
        const unsigned short* __restrict__ WtH,   // [128 cols][320 k] bf16 hi
        const unsigned short* __restrict__ WtL,   // lo
        const float* __restrict__ bs, const float* __restrict__ bn,
        const float* __restrict__ omega, const float* __restrict__ phase) {
    __shared__ float Abuf[3][128][32];        // 3 x 16 KB, bank-rotated slots
    __shared__ unsigned short teH[64][72];    // stride 72 shorts -> 2-way alias
    __shared__ unsigned short teL[64][72];

    const int tid  = threadIdx.x;
    const int e0   = blockIdx.x * 64;
    const int lane = tid & 63;
    const int w    = tid >> 6;
    const int wr   = w >> 1, wc = w & 1;
    const int krow = lane & 15;
    const int kgrp = lane >> 4;

    // ---- time encoding: 64 edges x 64 td, split hi/lo bf16 ----
    {
        const int tl = tid & 63;
        const int j0 = (tid >> 6) * 16;
        const float tval = ts[min(e0 + tl, EE - 1)];
#pragma unroll
        for (int j = 0; j < 16; j += 2) {
            int jj = j0 + j;
            float c0 = cosf(fmaf(tval, omega[jj],     phase[jj]));
            float c1 = cosf(fmaf(tval, omega[jj + 1], phase[jj + 1]));
            unsigned u0 = __float_as_uint(c0), u1 = __float_as_uint(c1);
            *(unsigned*)&teH[tl][jj] = (u0 >> 16) | (u1 & 0xFFFF0000u);
            float r0 = c0 - __uint_as_float(u0 & 0xFFFF0000u);
            float r1 = c1 - __uint_as_float(u1 & 0xFFFF0000u);
            *(unsigned*)&teL[tl][jj] =
                (unsigned)f2bf_rne(r0) | ((unsigned)f2bf_rne(r1) << 16);
        }
    }
    // te writes must be lgkm-retired before the first cross-wave barrier
    asm volatile("s_waitcnt lgkmcnt(0)" ::: "memory");
    __builtin_amdgcn_sched_barrier(0);

    // ---- per-thread DMA row assignment: rows w*32+qq*8+(lane>>3) ----
    int nodeq[4];
    const float* gbF[4];   // LAYER1: nfeat[endpoint]; LAYER2: feat row
    const float* gbE[4];   // LAYER1: efeat row
#pragma unroll
    for (int qq = 0; qq < 4; ++qq) {
        int row = w * 32 + qq * 8 + (lane >> 3);
        int e = min(e0 + (row & 63), EE - 1);
        int node = (row < 64) ? src[e] : dst[e];
        nodeq[qq] = node;
        if (LAYER == 1) {
            gbF[qq] = nfeat + (size_t)node * 64;
            gbE[qq] = efeat + (size_t)e * 64;
        } else {
            gbF[qq] = ((row < 64) ? featS : featD) + (size_t)e * 128;
            gbE[qq] = nullptr;
        }
    }
    const int pslot = lane & 7;

    // DMA chunk j (0..7) into Abuf[j%3]; LDS slot holds global part
    // pg = (slot - row) & 7 (bank rotation, inverted on the source address).
    auto dma = [&](int j) {
#pragma unroll
        for (int qq = 0; qq < 4; ++qq) {
            int row = w * 32 + qq * 8 + (lane >> 3);
            int pg = (pslot - row) & 7;
            const float* gsrc;
            if (j < 4) {
                if (LAYER == 1)
                    gsrc = (j < 2) ? (gbF[qq] + j * 32 + pg * 4)
                                   : (gbE[qq] + (j - 2) * 32 + pg * 4);
                else
                    gsrc = gbF[qq] + j * 32 + pg * 4;
            } else {
                gsrc = mean + (size_t)nodeq[qq] * 128 + (j - 4) * 32 + pg * 4;
            }
            lds_dma16(gsrc, &Abuf[j % 3][(w * 4 + qq) * 8][0]);
        }
    };

    f32x4 acc[4][4] = {};

    // prologue: 2 chunks in flight; drain DMA(0) only
    dma(0);
    dma(1);
    asm volatile("s_waitcnt vmcnt(4)" ::: "memory");
    __builtin_amdgcn_sched_barrier(0);

    // ---- DMA-fed chunks j = 0..7 ----
#pragma unroll
    for (int j = 0; j < 8; ++j) {
        const int kb = (j < 4) ? j * 32 : 192 + (j - 4) * 32;
        __builtin_amdgcn_s_barrier();     // buf[(j+2)%3] free; DMA(j) visible
        __builtin_amdgcn_sched_barrier(0);

        const int koff = kb + kgrp * 8;
        short8v Bh[4], Bl[4];
#pragma unroll
        for (int ct = 0; ct < 4; ++ct) {
            int c = wc * 64 + ct * 16 + krow;
            Bh[ct] = *(const short8v*)(WtH + (size_t)c * 320 + koff);
            Bl[ct] = *(const short8v*)(WtL + (size_t)c * 320 + koff);
        }
        __builtin_amdgcn_sched_barrier(0);
        if (j < 6) dma(j + 2);
        __builtin_amdgcn_sched_barrier(0);
        if (j < 7) { asm volatile("s_waitcnt vmcnt(4)" ::: "memory"); }
        else       { asm volatile("s_waitcnt vmcnt(0)" ::: "memory"); }
        __builtin_amdgcn_sched_barrier(0);

        short8v Ah[4], Al[4];
        const int b = j % 3;
#pragma unroll
        for (int rt = 0; rt < 4; ++rt) {
            int row = wr * 64 + rt * 16 + krow;
            float4 x0 = *(const float4*)&Abuf[b][row][(((2 * kgrp)     + row) & 7) * 4];
            float4 x1 = *(const float4*)&Abuf[b][row][(((2 * kgrp + 1) + row) & 7) * 4];
            split8(x0, x1, &Ah[rt], &Al[rt]);
        }
#pragma unroll
        for (int ct = 0; ct < 4; ++ct)
#pragma unroll
            for (int rt = 0; rt < 4; ++rt) {
                acc[rt][ct] = __builtin_amdgcn_mfma_f32_16x16x32_bf16(Ah[rt], Bh[ct], acc[rt][ct], 0, 0, 0);
                acc[rt][ct] = __builtin_amdgcn_mfma_f32_16x16x32_bf16(Ah[rt], Bl[ct], acc[rt][ct], 0, 0, 0);
                acc[rt][ct] = __builtin_amdgcn_mfma_f32_16x16x32_bf16(Al[rt], Bh[ct], acc[rt][ct], 0, 0, 0);
            }
    }

    // ---- te chunks (k = 128, 160), pure LDS+VALU+MFMA tail ----
#pragma unroll
    for (int tc = 0; tc < 2; ++tc) {
        const int kb = 128 + tc * 32;
        const int koff = kb + kgrp * 8;
        const int kt = tc * 32 + kgrp * 8;
        short8v Bh[4], Bl[4];
#pragma unroll
        for (int ct = 0; ct < 4; ++ct) {
            int c = wc * 64 + ct * 16 + krow;
            Bh[ct] = *(const short8v*)(WtH + (size_t)c * 320 + koff);
            Bl[ct] = *(const short8v*)(WtL + (size_t)c * 320 + koff);
        }
        short8v Ah[4], Al[4];
#pragma unroll
        for (int rt = 0; rt < 4; ++rt) {
            int el = rt * 16 + krow;                  // src & dst share te
            Ah[rt] = *(const short8v*)&teH[el][kt];
            Al[rt] = *(const short8v*)&teL[el][kt];
        }
#pragma unroll
        for (int ct = 0; ct < 4; ++ct)
#pragma unroll
            for (int rt = 0; rt < 4; ++rt) {
                acc[rt][ct] = __builtin_amdgcn_mfma_f32_16x16x32_bf16(Ah[rt], Bh[ct], acc[rt][ct], 0, 0, 0);
                acc[rt][ct] = __builtin_amdgcn_mfma_f32_16x16x32_bf16(Ah[rt], Bl[ct], acc[rt][ct], 0, 0, 0);
                acc[rt][ct] = __builtin_amdgcn_mfma_f32_16x16x32_bf16(Al[rt], Bh[ct], acc[rt][ct], 0, 0, 0);
            }
    }

    // ---- epilogue: + (b_self + b_neigh), relu, store (no gathers) ----
    float bcol[4];
#pragma unroll
    for (int ct = 0; ct < 4; ++ct) {
        int col = wc * 64 + ct * 16 + krow;
        bcol[ct] = bs[col] + bn[col];
    }
#pragma unroll
    for (int rt = 0; rt < 4; ++rt)
#pragma unroll
        for (int jj = 0; jj < 4; ++jj) {
            int row = wr * 64 + rt * 16 + kgrp * 4 + jj;
            int e = e0 + (row & 63);
            if (e < EE) {
                float* op = ((row < 64) ? outS : outD) + (size_t)e * 128;
#pragma unroll
                for (int ct = 0; ct < 4; ++ct) {
                    int col = wc * 64 + ct * 16 + krow;
                    op[col] = fmaxf(acc[rt][ct][jj] + bcol[ct], 0.f);
                }
            }
        }
}

// ---------------------------------------------------------------------------
extern "C" void kernel_launch(void* const* d_in, const int* in_sizes, int n_in,
                              void* d_out, int out_size, void* d_ws, size_t ws_size,
                              hipStream_t stream) {
    const float* nfeat = (const float*)d_in[0];
    const float* efeat = (const float*)d_in[1];
    const int*   src   = (const int*)d_in[2];
    const int*   dst   = (const int*)d_in[3];
    const float* ts    = (const float*)d_in[4];
    const float* Wself[2]  = {(const float*)d_in[5],  (const float*)d_in[11]};
    const float* bself[2]  = {(const float*)d_in[6],  (const float*)d_in[12]};
    const float* Wneigh[2] = {(const float*)d_in[7],  (const float*)d_in[13]};
    const float* bneigh[2] = {(const float*)d_in[8],  (const float*)d_in[14]};
    const float* omega[2]  = {(const float*)d_in[9],  (const float*)d_in[15]};
    const float* phase[2]  = {(const float*)d_in[10], (const float*)d_in[16]};

    // d_out doubles as the edge-feature ping-pong storage (in-place layer 2).
    float* outS = (float*)d_out;                   // src_feat  [E,128]
    float* outD = outS + (size_t)EE * 128;         // dst_feat  [E,128]

    // workspace: mean | pos | inc | fused split-bf16 weights (~90.3 MB)
    float* mean = (float*)d_ws;
    int*   pos  = (int*)(mean + (size_t)NN * 128);
    int2*  inc  = (int2*)(pos + NN);
    unsigned short* wb = (unsigned short*)(inc + (size_t)NN * CAP);
    unsigned short* WH[2] = {wb,                 wb + 2 * 320 * 128};
    unsigned short* WL[2] = {wb + 320 * 128,     wb + 3 * 320 * 128};

    hipMemsetAsync(pos, 0, NN * sizeof(int), stream);
    k_build<<<(EE + 255) / 256, 256, 0, stream>>>(src, dst, pos, inc);
    for (int l = 0; l < 2; ++l)
        k_wt2<<<(320 * 128 + 255) / 256, 256, 0, stream>>>(Wself[l], Wneigh[l], WH[l], WL[l]);

    // ---- layer 1 ----
    k_agg<1><<<(NN * 64 + 255) / 256, 256, 0, stream>>>(outS, outD, nfeat, efeat,
                                                        pos, inc, mean);
    k_edge_fused<1><<<(EE + 63) / 64, 256, 0, stream>>>(outS, outD, nfeat, efeat, mean,
                                                        outS, outD, src, dst, ts,
                                                        WH[0], WL[0], bself[0], bneigh[0],
                                                        omega[0], phase[0]);

    // ---- layer 2 (ping-pong rows, in place) ----
    k_agg<2><<<(NN * 64 + 255) / 256, 256, 0, stream>>>(outS, outD, nfeat, efeat,
                                                        pos, inc, mean);
    k_edge_fused<2><<<(EE + 63) / 64, 256, 0, stream>>>(outS, outD, nfeat, efeat, mean,
                                                        outS, outD, src, dst, ts,
                                                        WH[1], WL[1], bself[1], bneigh[1],
                                                        omega[1], phase[1]);
}

// Round 5
// 1710.948 us; speedup vs baseline: 1.2508x; 1.0837x over previous
//
#include <hip/hip_runtime.h>
#include <cstdint>
#include <cmath>

// Problem constants (match reference)
#define NN 100000   // nodes
#define EE 500000   // edges
// DN=64, DE=64, D=128, TD=64.  Fused K = 192 (self) + 128 (neigh) = 320.
#define CAP 48      // incidence capacity/node (deg ~ Poisson(10): P(>=48) ~ 1e-20)

typedef __attribute__((ext_vector_type(8))) short short8v;   // 8 bf16 (4 VGPRs)
typedef __attribute__((ext_vector_type(4))) float f32x4;     // MFMA accumulator

// float -> bf16 round-to-nearest-even (bit trick; inputs finite)
static __device__ __forceinline__ unsigned short f2bf_rne(float x) {
    unsigned u = __float_as_uint(x);
    u += 0x7FFFu + ((u >> 16) & 1u);
    return (unsigned short)(u >> 16);
}

// pack 8 consecutive floats into hi/lo bf16 vectors (hi=truncate, lo=RNE residual)
static __device__ __forceinline__ void split8(float4 a, float4 b,
                                              short8v* hi, short8v* lo) {
    union { short8v v; unsigned u[4]; } H, L;
    float f[8] = {a.x, a.y, a.z, a.w, b.x, b.y, b.z, b.w};
#pragma unroll
    for (int p = 0; p < 4; ++p) {
        unsigned u0 = __float_as_uint(f[2 * p]);
        unsigned u1 = __float_as_uint(f[2 * p + 1]);
        H.u[p] = (u0 >> 16) | (u1 & 0xFFFF0000u);
        float r0 = f[2 * p]     - __uint_as_float(u0 & 0xFFFF0000u);
        float r1 = f[2 * p + 1] - __uint_as_float(u1 & 0xFFFF0000u);
        L.u[p] = (unsigned)f2bf_rne(r0) | ((unsigned)f2bf_rne(r1) << 16);
    }
    *hi = H.v; *lo = L.v;
}

// async 16B global->LDS (dest: wave-uniform base + lane*16; src: per-lane)
static __device__ __forceinline__ void lds_dma16(const void* g, void* l) {
    __builtin_amdgcn_global_load_lds(
        (const __attribute__((address_space(1))) unsigned int*)g,
        (__attribute__((address_space(3))) unsigned int*)l, 16, 0, 0);
}

// ---------------------------------------------------------------------------
// Build per-node incidence lists: entry = {(e<<1)|side, other_node}.
__global__ __launch_bounds__(256) void k_build(const int* __restrict__ src,
                                               const int* __restrict__ dst,
                                               int* __restrict__ pos,
                                               int2* __restrict__ inc) {
    int e = blockIdx.x * 256 + threadIdx.x;
    if (e >= EE) return;
    int s = src[e], d = dst[e];
    int sl = atomicAdd(&pos[s], 1);
    if (sl < CAP) inc[(size_t)s * CAP + sl] = make_int2((e << 1) | 1, d);
    int dl = atomicAdd(&pos[d], 1);
    if (dl < CAP) inc[(size_t)d * CAP + dl] = make_int2((e << 1), s);
}

// ---------------------------------------------------------------------------
// Fused-weight prep: rows 0..191 = W_self [192][128], rows 192..319 = W_neigh
// [128][128].  Output: interleaved split-bf16 [128 cols][40 grps][hi8|lo8] so
// Bh/Bl for one k-group are two ADJACENT 16-B loads (one 32-B span, one line).
__global__ __launch_bounds__(256) void k_wt2(const float* __restrict__ Wself,
                                             const float* __restrict__ Wneigh,
                                             unsigned short* __restrict__ WI) {
    int idx = blockIdx.x * 256 + threadIdx.x;
    if (idx >= 320 * 128) return;
    int k = idx >> 7, c = idx & 127;
    float x = (k < 192) ? Wself[k * 128 + c] : Wneigh[(k - 192) * 128 + c];
    unsigned u = __float_as_uint(x);
    int grp = k >> 3, pos = k & 7;
    size_t base = (size_t)c * 640 + grp * 16;
    WI[base + pos] = (unsigned short)(u >> 16);
    float r = x - __uint_as_float(u & 0xFFFF0000u);
    WI[base + 8 + pos] = f2bf_rne(r);
}

// ---------------------------------------------------------------------------
// Aggregation: one wave per node, quarter-wave (16 lanes x 32B) per entry,
// +1-deep entry prefetch.  LAYER1 gathers [nfeat[other], efeat[e]]; LAYER2
// gathers ping-pong rows.
template <int LAYER>
__global__ __launch_bounds__(256) void k_agg(const float* __restrict__ featS,
                                             const float* __restrict__ featD,
                                             const float* __restrict__ nfeat,
                                             const float* __restrict__ efeat,
                                             const int* __restrict__ pos,
                                             const int2* __restrict__ inc,
                                             float* __restrict__ mean) {
    int w = (blockIdx.x * 256 + threadIdx.x) >> 6;   // node id
    int lane = threadIdx.x & 63;
    if (w >= NN) return;
    int q = lane >> 4, cl = lane & 15;               // channels cl*8 .. cl*8+7
    int d = pos[w];
    int dd = min(d, CAP);
    const int2* lst = inc + (size_t)w * CAP;
    float a0 = 0.f, a1 = 0.f, a2 = 0.f, a3 = 0.f;
    float a4 = 0.f, a5 = 0.f, a6 = 0.f, a7 = 0.f;
    int2 en = (q < dd) ? lst[q] : make_int2(0, 0);
    for (int j = q; j < dd; j += 4) {
        int2 nxt = (j + 4 < dd) ? lst[j + 4] : en;   // prefetch next entry
        int e = en.x >> 1, side = en.x & 1;
        const float* p;
        if (LAYER == 1) {
            p = (cl < 8) ? (nfeat + (size_t)en.y * 64 + cl * 8)
                         : (efeat + (size_t)e * 64 + (cl - 8) * 8);
        } else {
            p = (side ? featD : featS) + (size_t)e * 128 + cl * 8;
        }
        float4 v0 = *(const float4*)p;
        float4 v1 = *(const float4*)(p + 4);
        a0 += v0.x; a1 += v0.y; a2 += v0.z; a3 += v0.w;
        a4 += v1.x; a5 += v1.y; a6 += v1.z; a7 += v1.w;
        en = nxt;
    }
#pragma unroll
    for (int m = 16; m <= 32; m <<= 1) {
        a0 += __shfl_xor(a0, m); a1 += __shfl_xor(a1, m);
        a2 += __shfl_xor(a2, m); a3 += __shfl_xor(a3, m);
        a4 += __shfl_xor(a4, m); a5 += __shfl_xor(a5, m);
        a6 += __shfl_xor(a6, m); a7 += __shfl_xor(a7, m);
    }
    if (q == 0) {
        float inv = 1.0f / fmaxf((float)d, 1.0f);
        float4 r0, r1;
        r0.x = a0 * inv; r0.y = a1 * inv; r0.z = a2 * inv; r0.w = a3 * inv;
        r1.x = a4 * inv; r1.y = a5 * inv; r1.z = a6 * inv; r1.w = a7 * inv;
        *(float4*)(mean + (size_t)w * 128 + cl * 8) = r0;
        *(float4*)(mean + (size_t)w * 128 + cl * 8 + 4) = r1;
    }
}

// ---------------------------------------------------------------------------
// Fused edge update: out = relu(concat(prev, te, mean[endpoint]) @ Wcat + b).
// Block = 64 edges -> 128 rows x 128 cols; 4 waves (2x2), each 64 rows x 64
// cols (rt=4, ct=4), split-bf16 MFMA (3 terms).  K = 320, 10 chunks of 32:
// DMA chunks j=0..7 (feat + mean-gather), te chunks (k=128,160) at the end.
// Depth-1 DMA pipeline, 2 LDS A-buffers, raw s_barrier + counted vmcnt(4).
// Occupancy target: 3 blocks/CU (LDS 50 KB, VGPR forced <=170 by bounds).
template <int LAYER>
__global__ __launch_bounds__(256, 3) void k_edge_fused(
        const float* __restrict__ featS,
        const float* __restrict__ nfeat, const float* __restrict__ efeat,
        const float* __restrict__ mean,
        float* __restrict__ outS, float* __restrict__ outD,
        const int* __restrict__ src, const int* __restrict__ dst,
        const float* __restrict__ ts,
        const unsigned short* __restrict__ WI,    // [128 c][40 grp][hi8|lo8]
        const float* __restrict__ bs, const float* __restrict__ bn,
        const float* __restrict__ omega, const float* __restrict__ phase) {
    __shared__ float Abuf[2][128][32];        // 2 x 16 KB, bank-rotated slots
    __shared__ unsigned short teH[64][72];    // stride 72 shorts -> spread banks
    __shared__ unsigned short teL[64][72];

    const int tid  = threadIdx.x;
    const int e0   = blockIdx.x * 64;
    const int lane = tid & 63;
    const int w    = tid >> 6;
    const int wr   = w >> 1, wc = w & 1;
    const int krow = lane & 15;
    const int kgrp = lane >> 4;
    const int pslot = lane & 7;

    // ---- per-thread DMA row offsets (rows w*32+qq*8+(lane>>3)) ----
    unsigned offF[4], offE[4], offM[4];       // byte offsets
#pragma unroll
    for (int qq = 0; qq < 4; ++qq) {
        int row = w * 32 + qq * 8 + (lane >> 3);
        int e = min(e0 + (row & 63), EE - 1);
        int node = (row < 64) ? src[e] : dst[e];
        offM[qq] = (unsigned)node * 512u;
        if (LAYER == 1) {
            offF[qq] = (unsigned)node * 256u;
            offE[qq] = (unsigned)e * 256u;
        } else {
            offF[qq] = ((row < 64) ? 0u : (unsigned)EE * 512u) + (unsigned)e * 512u;
            offE[qq] = 0u;
        }
    }

    // DMA chunk j (0..7) into Abuf[j&1]; LDS slot s holds global part (s-row)&7
    auto dma = [&](int j) {
#pragma unroll
        for (int qq = 0; qq < 4; ++qq) {
            int row = w * 32 + qq * 8 + (lane >> 3);
            int pg = (pslot - row) & 7;
            const char* g;
            if (j < 4) {
                if (LAYER == 1)
                    g = (j < 2) ? ((const char*)nfeat + offF[qq] + j * 128 + pg * 16)
                                : ((const char*)efeat + offE[qq] + (j - 2) * 128 + pg * 16);
                else
                    g = (const char*)featS + offF[qq] + j * 128 + pg * 16;
            } else {
                g = (const char*)mean + offM[qq] + (j - 4) * 128 + pg * 16;
            }
            lds_dma16(g, &Abuf[j & 1][(w * 4 + qq) * 8][0]);
        }
    };

    dma(0);   // chunk-0 HBM latency hides under the te computation below

    // ---- time encoding: 64 edges x 64 td, split hi/lo bf16 ----
    {
        const int tl = tid & 63;
        const int j0 = (tid >> 6) * 16;
        const float tval = ts[min(e0 + tl, EE - 1)];
#pragma unroll
        for (int j = 0; j < 16; j += 2) {
            int jj = j0 + j;
            float c0 = cosf(fmaf(tval, omega[jj],     phase[jj]));
            float c1 = cosf(fmaf(tval, omega[jj + 1], phase[jj + 1]));
            unsigned u0 = __float_as_uint(c0), u1 = __float_as_uint(c1);
            *(unsigned*)&teH[tl][jj] = (u0 >> 16) | (u1 & 0xFFFF0000u);
            float r0 = c0 - __uint_as_float(u0 & 0xFFFF0000u);
            float r1 = c1 - __uint_as_float(u1 & 0xFFFF0000u);
            *(unsigned*)&teL[tl][jj] =
                (unsigned)f2bf_rne(r0) | ((unsigned)f2bf_rne(r1) << 16);
        }
    }
    asm volatile("s_waitcnt lgkmcnt(0)" ::: "memory");
    __builtin_amdgcn_sched_barrier(0);

    f32x4 acc[4][4] = {};

    // ---- DMA-fed chunks j = 0..7 (depth-1 pipeline) ----
#pragma unroll
    for (int j = 0; j < 8; ++j) {
        // drain own dma(j) (issued ~1 chunk ago); barrier -> all waves' dma(j)
        // visible AND chunk j-1 reads complete (safe to overwrite other buf)
        asm volatile("s_waitcnt vmcnt(0) lgkmcnt(0)" ::: "memory");
        __builtin_amdgcn_sched_barrier(0);
        __builtin_amdgcn_s_barrier();
        __builtin_amdgcn_sched_barrier(0);

        const int kb = (j < 4) ? j * 32 : 192 + (j - 4) * 32;
        const int goff = ((kb >> 3) + kgrp) * 16;    // interleaved grp offset
        short8v Bh[4], Bl[4];
#pragma unroll
        for (int ct = 0; ct < 4; ++ct) {
            int c = wc * 64 + ct * 16 + krow;
            const unsigned short* bp = WI + (size_t)c * 640 + goff;
            Bh[ct] = *(const short8v*)bp;
            Bl[ct] = *(const short8v*)(bp + 8);
        }
        __builtin_amdgcn_sched_barrier(0);
        if (j < 7) dma(j + 1);                       // issued AFTER B loads
        __builtin_amdgcn_sched_barrier(0);

        const int b = j & 1;
#pragma unroll
        for (int half = 0; half < 2; ++half) {
            short8v Ah[2], Al[2];
#pragma unroll
            for (int r2 = 0; r2 < 2; ++r2) {
                int row = wr * 64 + (half * 2 + r2) * 16 + krow;
                float4 x0 = *(const float4*)&Abuf[b][row][(((2 * kgrp)     + row) & 7) * 4];
                float4 x1 = *(const float4*)&Abuf[b][row][(((2 * kgrp + 1) + row) & 7) * 4];
                split8(x0, x1, &Ah[r2], &Al[r2]);
            }
            if (half == 0) {
                // counted wait: drains B(j) (issued first), leaves dma(j+1)
                if (j < 7) { asm volatile("s_waitcnt vmcnt(4)" ::: "memory"); }
                else       { asm volatile("s_waitcnt vmcnt(0)" ::: "memory"); }
                __builtin_amdgcn_sched_barrier(0);
            }
#pragma unroll
            for (int ct = 0; ct < 4; ++ct)
#pragma unroll
                for (int r2 = 0; r2 < 2; ++r2) {
                    int rt = half * 2 + r2;
                    acc[rt][ct] = __builtin_amdgcn_mfma_f32_16x16x32_bf16(Ah[r2], Bh[ct], acc[rt][ct], 0, 0, 0);
                    acc[rt][ct] = __builtin_amdgcn_mfma_f32_16x16x32_bf16(Ah[r2], Bl[ct], acc[rt][ct], 0, 0, 0);
                    acc[rt][ct] = __builtin_amdgcn_mfma_f32_16x16x32_bf16(Al[r2], Bh[ct], acc[rt][ct], 0, 0, 0);
                }
        }
    }

    // ---- te chunks (k = 128, 160), pure LDS+VALU+MFMA tail ----
#pragma unroll
    for (int tc = 0; tc < 2; ++tc) {
        const int kb = 128 + tc * 32;
        const int goff = ((kb >> 3) + kgrp) * 16;
        const int kt = tc * 32 + kgrp * 8;
        short8v Bh[4], Bl[4];
#pragma unroll
        for (int ct = 0; ct < 4; ++ct) {
            int c = wc * 64 + ct * 16 + krow;
            const unsigned short* bp = WI + (size_t)c * 640 + goff;
            Bh[ct] = *(const short8v*)bp;
            Bl[ct] = *(const short8v*)(bp + 8);
        }
#pragma unroll
        for (int half = 0; half < 2; ++half) {
            short8v Ah[2], Al[2];
#pragma unroll
            for (int r2 = 0; r2 < 2; ++r2) {
                int el = (half * 2 + r2) * 16 + krow;     // src & dst share te
                Ah[r2] = *(const short8v*)&teH[el][kt];
                Al[r2] = *(const short8v*)&teL[el][kt];
            }
#pragma unroll
            for (int ct = 0; ct < 4; ++ct)
#pragma unroll
                for (int r2 = 0; r2 < 2; ++r2) {
                    int rt = half * 2 + r2;
                    acc[rt][ct] = __builtin_amdgcn_mfma_f32_16x16x32_bf16(Ah[r2], Bh[ct], acc[rt][ct], 0, 0, 0);
                    acc[rt][ct] = __builtin_amdgcn_mfma_f32_16x16x32_bf16(Ah[r2], Bl[ct], acc[rt][ct], 0, 0, 0);
                    acc[rt][ct] = __builtin_amdgcn_mfma_f32_16x16x32_bf16(Al[r2], Bh[ct], acc[rt][ct], 0, 0, 0);
                }
        }
    }

    // ---- epilogue: + (b_self + b_neigh), relu, store (no gathers) ----
    float bcol[4];
#pragma unroll
    for (int ct = 0; ct < 4; ++ct) {
        int col = wc * 64 + ct * 16 + krow;
        bcol[ct] = bs[col] + bn[col];
    }
#pragma unroll
    for (int rt = 0; rt < 4; ++rt)
#pragma unroll
        for (int jj = 0; jj < 4; ++jj) {
            int row = wr * 64 + rt * 16 + kgrp * 4 + jj;
            int e = e0 + (row & 63);
            if (e < EE) {
                float* op = ((row < 64) ? outS : outD) + (size_t)e * 128;
#pragma unroll
                for (int ct = 0; ct < 4; ++ct) {
                    int col = wc * 64 + ct * 16 + krow;
                    op[col] = fmaxf(acc[rt][ct][jj] + bcol[ct], 0.f);
                }
            }
        }
}

// ---------------------------------------------------------------------------
extern "C" void kernel_launch(void* const* d_in, const int* in_sizes, int n_in,
                              void* d_out, int out_size, void* d_ws, size_t ws_size,
                              hipStream_t stream) {
    const float* nfeat = (const float*)d_in[0];
    const float* efeat = (const float*)d_in[1];
    const int*   src   = (const int*)d_in[2];
    const int*   dst   = (const int*)d_in[3];
    const float* ts    = (const float*)d_in[4];
    const float* Wself[2]  = {(const float*)d_in[5],  (const float*)d_in[11]};
    const float* bself[2]  = {(const float*)d_in[6],  (const float*)d_in[12]};
    const float* Wneigh[2] = {(const float*)d_in[7],  (const float*)d_in[13]};
    const float* bneigh[2] = {(const float*)d_in[8],  (const float*)d_in[14]};
    const float* omega[2]  = {(const float*)d_in[9],  (const float*)d_in[15]};
    const float* phase[2]  = {(const float*)d_in[10], (const float*)d_in[16]};

    // d_out doubles as the edge-feature ping-pong storage (in-place layer 2).
    float* outS = (float*)d_out;                   // src_feat  [E,128]
    float* outD = outS + (size_t)EE * 128;         // dst_feat  [E,128]

    // workspace: mean | pos | inc | interleaved split-bf16 weights (~90.3 MB)
    float* mean = (float*)d_ws;
    int*   pos  = (int*)(mean + (size_t)NN * 128);
    int2*  inc  = (int2*)(pos + NN);
    unsigned short* wi = (unsigned short*)(inc + (size_t)NN * CAP);
    unsigned short* WIl[2] = {wi, wi + (size_t)128 * 640};

    hipMemsetAsync(pos, 0, NN * sizeof(int), stream);
    k_build<<<(EE + 255) / 256, 256, 0, stream>>>(src, dst, pos, inc);
    for (int l = 0; l < 2; ++l)
        k_wt2<<<(320 * 128 + 255) / 256, 256, 0, stream>>>(Wself[l], Wneigh[l], WIl[l]);

    // ---- layer 1 ----
    k_agg<1><<<(NN * 64 + 255) / 256, 256, 0, stream>>>(outS, outD, nfeat, efeat,
                                                        pos, inc, mean);
    k_edge_fused<1><<<(EE + 63) / 64, 256, 0, stream>>>(outS, nfeat, efeat, mean,
                                                        outS, outD, src, dst, ts,
                                                        WIl[0], bself[0], bneigh[0],
                                                        omega[0], phase[0]);

    // ---- layer 2 (ping-pong rows, in place) ----
    k_agg<2><<<(NN * 64 + 255) / 256, 256, 0, stream>>>(outS, outD, nfeat, efeat,
                                                        pos, inc, mean);
    k_edge_fused<2><<<(EE + 63) / 64, 256, 0, stream>>>(outS, nfeat, efeat, mean,
                                                        outS, outD, src, dst, ts,
                                                        WIl[1], bself[1], bneigh[1],
                                                        omega[1], phase[1]);
}